// Round 5
// baseline (991.856 us; speedup 1.0000x reference)
//
#include <hip/hip_runtime.h>

typedef _Float16 half8 __attribute__((ext_vector_type(8)));
typedef _Float16 half4 __attribute__((ext_vector_type(4)));
typedef _Float16 half2 __attribute__((ext_vector_type(2)));
typedef float    f32x4 __attribute__((ext_vector_type(4)));
typedef float    f32x2 __attribute__((ext_vector_type(2)));
typedef unsigned u32x2 __attribute__((ext_vector_type(2)));

#define TMASK ((1u << 19) - 1u)       // T = 2^19
#define HSTRIDE 136                    // fallback-kernel LDS stride
constexpr float SCALE = 65536.0f;      // activation scale: keeps f16 out of subnormal range
constexpr float INV_SCALE = 1.0f / 65536.0f;

// ---------------------------------------------------------------------------
// Prep: (a) fp32 tables -> f16 pre-scaled by SCALE, (b) weights -> frag f16.
// Fragment layout [tile][lane][8 f16]: value = W[k*N + n] with
//   n(outchan) = nt*16 + (lane&15), k(inchan) = kt*32 + (lane>>4)*8 + j.
// This serves as B-frag (act@W form) AND as A-frag (W-as-A form): for
// mfma A-operand, m=lane&15 -> outchan, k=quad*8+j -> inchan. Same bytes.
// Tiles: W0:0..7, W1:8..39, W2:40..71, W3:72..103, Wout(pad N->16):104..107.
// ---------------------------------------------------------------------------
__global__ void prep_kernel(const float* __restrict__ W0, const float* __restrict__ W1,
                            const float* __restrict__ W2, const float* __restrict__ W3,
                            const float* __restrict__ Wm,
                            const float* __restrict__ b0, const float* __restrict__ b1,
                            const float* __restrict__ b2, const float* __restrict__ b3,
                            const float* __restrict__ bm,
                            _Float16* __restrict__ wsW, float* __restrict__ wsB,
                            const float* __restrict__ tables, _Float16* __restrict__ tabF,
                            int tabBlocks)
{
    if ((int)blockIdx.x < tabBlocks) {
        size_t i = (size_t)blockIdx.x * 256 + threadIdx.x;
        f32x4 v = ((const f32x4*)tables)[i];
        half4 o;
        o[0] = (_Float16)(v.x * SCALE);
        o[1] = (_Float16)(v.y * SCALE);
        o[2] = (_Float16)(v.z * SCALE);
        o[3] = (_Float16)(v.w * SCALE);
        ((half4*)tabF)[i] = o;
        return;
    }
    int gid = ((int)blockIdx.x - tabBlocks) * 256 + threadIdx.x;
    if (gid < 6912) {                       // 108 tiles * 64 lanes
        int tile = gid >> 6, lane = gid & 63;
        const float* W; int K, N, toff;
        if (tile < 8)        { W = W0; K = 32;  N = 128; toff = 0;   }
        else if (tile < 40)  { W = W1; K = 128; N = 128; toff = 8;   }
        else if (tile < 72)  { W = W2; K = 128; N = 128; toff = 40;  }
        else if (tile < 104) { W = W3; K = 128; N = 128; toff = 72;  }
        else                 { W = Wm; K = 128; N = 4;   toff = 104; }
        int tt = tile - toff;
        int KT = K >> 5;
        int nt = tt / KT, kt = tt - nt * KT;
        int n = nt * 16 + (lane & 15);
        int kbase = kt * 32 + (lane >> 4) * 8;
        half8 v;
        #pragma unroll
        for (int j = 0; j < 8; j++) {
            int k = kbase + j;
            float w = (n < N) ? W[k * N + n] : 0.0f;
            v[j] = (_Float16)w;
        }
        *(half8*)(wsW + (size_t)gid * 8) = v;
    } else if (gid < 6912 + 528) {
        int i = gid - 6912;
        float v;
        if (i < 512) {
            int layer = i >> 7, n = i & 127;
            const float* b = (layer == 0) ? b0 : (layer == 1) ? b1 : (layer == 2) ? b2 : b3;
            v = b[n] * SCALE;
        } else {
            int n = i - 512;
            v = (n < 4) ? bm[n] * SCALE : 0.0f;
        }
        wsB[i] = v;
    }
}

// ---------------------------------------------------------------------------
// Encode kernel, level-major with XCD affinity (lvl0 = bid&7 pairs coarse l
// with fine l+8 on one XCD). 8B x-pair slot loads + masked odd loads (R4).
// R5: fine-level gathers use NONTEMPORAL loads (L1 no-allocate) and issue
// first — fine lines are use-once and were evicting the coarse working set
// from the 32KB L1.
// ---------------------------------------------------------------------------
__global__ __launch_bounds__(256, 4) void encode_kernel(
    const float* __restrict__ pos, const float* __restrict__ bmn, const float* __restrict__ bmx,
    const _Float16* __restrict__ tab, _Float16* __restrict__ feat, int npts)
{
    const int lvl0 = (int)(blockIdx.x & 7);
    const int p = (int)(blockIdx.x >> 3) * 256 + (int)threadIdx.x;
    const float bx = bmn[0], by = bmn[1], bz = bmn[2];
    const float nx = (pos[(size_t)p * 3 + 0] - bx) / (bmx[0] - bx);
    const float ny = (pos[(size_t)p * 3 + 1] - by) / (bmx[1] - by);
    const float nz = (pos[(size_t)p * 3 + 2] - bz) / (bmx[2] - bz);
    constexpr float RESL[16] = {16.f, 20.f, 25.f, 32.f, 40.f, 50.f, 64.f, 80.f,
                                101.f, 128.f, 161.f, 203.f, 256.f, 322.f, 406.f, 512.f};
    const int l0 = lvl0, l1 = lvl0 + 8;
    const _Float16* tblA = tab + ((size_t)l0 << 20);   // coarse
    const _Float16* tblB = tab + ((size_t)l1 << 20);   // fine

    unsigned idxAE[4], idxAO[4], idxBE[4], idxBO[4];
    bool oddA, oddB;
    float txA, tyA, tzA, txB, tyB, tzB;
    {
        const float res = RESL[l1];       // fine first
        float xs = nx * res, ys = ny * res, zs = nz * res;
        float fx = floorf(xs), fy = floorf(ys), fz = floorf(zs);
        unsigned xi = (unsigned)fx, yi = (unsigned)fy, zi = (unsigned)fz;
        txB = xs - fx; tyB = ys - fy; tzB = zs - fz;
        unsigned hy0 = yi * 2654435761u, hy1 = (yi + 1u) * 2654435761u;
        unsigned hz0 = zi * 805459861u,  hz1 = (zi + 1u) * 805459861u;
        unsigned hyz[4] = {hy0 ^ hz0, hy1 ^ hz0, hy0 ^ hz1, hy1 ^ hz1};
        unsigned e = (xi + 1u) & ~1u;
        unsigned o = xi | 1u;
        oddB = (xi & 1u) != 0u;
        #pragma unroll
        for (int g = 0; g < 4; g++) {
            idxBE[g] = (e ^ hyz[g]) & TMASK;
            idxBO[g] = (o ^ hyz[g]) & TMASK;
        }
    }
    {
        const float res = RESL[l0];
        float xs = nx * res, ys = ny * res, zs = nz * res;
        float fx = floorf(xs), fy = floorf(ys), fz = floorf(zs);
        unsigned xi = (unsigned)fx, yi = (unsigned)fy, zi = (unsigned)fz;
        txA = xs - fx; tyA = ys - fy; tzA = zs - fz;
        unsigned hy0 = yi * 2654435761u, hy1 = (yi + 1u) * 2654435761u;
        unsigned hz0 = zi * 805459861u,  hz1 = (zi + 1u) * 805459861u;
        unsigned hyz[4] = {hy0 ^ hz0, hy1 ^ hz0, hy0 ^ hz1, hy1 ^ hz1};
        unsigned e = (xi + 1u) & ~1u;
        unsigned o = xi | 1u;
        oddA = (xi & 1u) != 0u;
        #pragma unroll
        for (int g = 0; g < 4; g++) {
            idxAE[g] = (e ^ hyz[g]) & TMASK;
            idxAO[g] = (o ^ hyz[g]) & TMASK;
        }
    }

    // ---- fine (nontemporal, issue first), then coarse ----
    u32x2 sB[4], sA[4];
    #pragma unroll
    for (int g = 0; g < 4; g++)
        sB[g] = __builtin_nontemporal_load((const u32x2*)(tblB + (size_t)(idxBE[g] & ~1u) * 2));
    #pragma unroll
    for (int g = 0; g < 4; g++)
        sA[g] = *(const u32x2*)(tblA + (size_t)(idxAE[g] & ~1u) * 2);

    unsigned oBu[4]; half2 oAv[4];
    if (oddB) {
        #pragma unroll
        for (int g = 0; g < 4; g++)
            oBu[g] = __builtin_nontemporal_load((const unsigned*)(tblB + (size_t)idxBO[g] * 2));
    }
    if (oddA) {
        #pragma unroll
        for (int g = 0; g < 4; g++)
            oAv[g] = *(const half2*)(tblA + (size_t)idxAO[g] * 2);
    }

    float wyzA[4] = {(1.0f - tyA) * (1.0f - tzA), tyA * (1.0f - tzA),
                     (1.0f - tyA) * tzA,          tyA * tzA};
    float wyzB[4] = {(1.0f - tyB) * (1.0f - tzB), tyB * (1.0f - tzB),
                     (1.0f - tyB) * tzB,          tyB * tzB};

    float a0 = 0.0f, a1 = 0.0f, b0 = 0.0f, b1 = 0.0f;
    #pragma unroll
    for (int g = 0; g < 4; g++) {
        union { unsigned u; half2 h; } lo, hi, ov;
        lo.u = sB[g][0]; hi.u = sB[g][1];
        bool pe = (idxBE[g] & 1u) != 0u;
        half2 fe  = pe ? hi.h : lo.h;
        half2 fe1 = pe ? lo.h : hi.h;
        ov.u = oddB ? oBu[g] : 0u;
        half2 fx0 = oddB ? ov.h : fe;
        half2 fx1 = oddB ? fe : fe1;
        float w0 = wyzB[g] * (1.0f - txB), w1 = wyzB[g] * txB;
        b0 += w0 * (float)fx0[0] + w1 * (float)fx1[0];
        b1 += w0 * (float)fx0[1] + w1 * (float)fx1[1];
    }
    {
        half2 ov; ov[0] = (_Float16)b0; ov[1] = (_Float16)b1;
        union { half2 h; unsigned u; } cv; cv.h = ov;
        __builtin_nontemporal_store(cv.u, (unsigned*)(feat + ((size_t)l1 * npts + p) * 2));
    }
    #pragma unroll
    for (int g = 0; g < 4; g++) {
        union { unsigned u; half2 h; } lo, hi;
        lo.u = sA[g][0]; hi.u = sA[g][1];
        bool pe = (idxAE[g] & 1u) != 0u;
        half2 fe  = pe ? hi.h : lo.h;
        half2 fe1 = pe ? lo.h : hi.h;
        half2 fx0 = oddA ? oAv[g] : fe;
        half2 fx1 = oddA ? fe : fe1;
        float w0 = wyzA[g] * (1.0f - txA), w1 = wyzA[g] * txA;
        a0 += w0 * (float)fx0[0] + w1 * (float)fx1[0];
        a1 += w0 * (float)fx0[1] + w1 * (float)fx1[1];
    }
    {
        half2 ov; ov[0] = (_Float16)a0; ov[1] = (_Float16)a1;
        union { half2 h; unsigned u; } cv; cv.h = ov;
        __builtin_nontemporal_store(cv.u, (unsigned*)(feat + ((size_t)l0 * npts + p) * 2));
    }
}

// ---------------------------------------------------------------------------
// New MLP kernel: swapped MFMA roles. D = W(A-frag) x act(B-frag).
//   A-frag (weights): m=lane&15 -> outchan, k=quad*8+j -> inchan (prep frags).
//   B-frag (act):     n=lane&15 -> point,   k=quad*8+j -> inchan.
//   D:                col=lane&15 -> point, row=quad*4+r -> outchan.
// Inter-layer transform D->B needs, per target lane (quad q, kt'):
//   source quads q' = 2(q&1)+{0,1}, source mt = 2kt'+(q>>1), regs r0..3
// i.e. 16 ds_write_b64 + 16 ds_read_b64 per layer, wave-private, NO barriers.
// ebuf stride 34 dwords/lane (8B aligned, banks spread).
// ---------------------------------------------------------------------------
#define ELANE 34   // dwords per lane in exchange buffer

template<int KT, int TOFF>
__device__ __forceinline__ void layer_fwd(half8 b[2][4], const half8* __restrict__ wf,
                                          const float* __restrict__ wsB, int li,
                                          unsigned* __restrict__ eb, int lane, int quad,
                                          unsigned srcA, unsigned srcB, int mtbase)
{
    f32x4 acc[8][2];
    #pragma unroll
    for (int mt = 0; mt < 8; mt++) {
        f32x4 bias = *(const f32x4*)&wsB[li * 128 + mt * 16 + quad * 4];
        half8 w[KT];
        #pragma unroll
        for (int kt = 0; kt < KT; kt++)
            w[kt] = wf[(size_t)(TOFF + mt * KT + kt) * 64 + lane];
        acc[mt][0] = bias;
        acc[mt][1] = bias;
        #pragma unroll
        for (int nt = 0; nt < 2; nt++)
            #pragma unroll
            for (int kt = 0; kt < KT; kt++)
                acc[mt][nt] = __builtin_amdgcn_mfma_f32_16x16x32_f16(w[kt], b[nt][kt], acc[mt][nt], 0, 0, 0);
    }
    // ReLU + pack to f16 pairs + publish (16 x ds_write_b64)
    unsigned* wptr = eb + lane * ELANE;
    #pragma unroll
    for (int mt = 0; mt < 8; mt++)
        #pragma unroll
        for (int nt = 0; nt < 2; nt++) {
            union { _Float16 h[4]; unsigned long long u64; } pk;
            #pragma unroll
            for (int r = 0; r < 4; r++)
                pk.h[r] = (_Float16)fmaxf(acc[mt][nt][r], 0.0f);
            *(unsigned long long*)(wptr + (mt * 2 + nt) * 2) = pk.u64;
        }
    // gather next-layer B-frags (16 x ds_read_b64); same-wave program order
    // guarantees write->read visibility without a barrier.
    #pragma unroll
    for (int nt = 0; nt < 2; nt++)
        #pragma unroll
        for (int ktp = 0; ktp < 4; ktp++) {
            int mt = 2 * ktp + mtbase;
            union { unsigned long long u64[2]; half8 v; } cv;
            cv.u64[0] = *(const unsigned long long*)(eb + srcA * ELANE + (mt * 2 + nt) * 2);
            cv.u64[1] = *(const unsigned long long*)(eb + srcB * ELANE + (mt * 2 + nt) * 2);
            b[nt][ktp] = cv.v;
        }
}

__global__ __launch_bounds__(256) void mlp_kernel(
    const unsigned* __restrict__ feat32, const half8* __restrict__ wf,
    const float* __restrict__ wsB, float* __restrict__ out, int npts)
{
    __shared__ unsigned ebuf[4 * 64 * ELANE];
    const int t = threadIdx.x;
    const int lane = t & 63, wv = t >> 6;
    const int col = lane & 15, quad = lane >> 4;
    const long base = (long)blockIdx.x * 128 + wv * 32;
    unsigned* eb = ebuf + wv * (64 * ELANE);
    const int q1 = 2 * (quad & 1);
    const unsigned srcA = (unsigned)(col + 16 * q1);
    const unsigned srcB = (unsigned)(col + 16 * (q1 + 1));
    const int mtbase = quad >> 1;

    // ---- layer-0 B-frags straight from feat (chan-major, coalesced) ----
    half8 b[2][4];
    #pragma unroll
    for (int nt = 0; nt < 2; nt++) {
        const long pt = base + nt * 16 + col;
        union { unsigned u4[4]; half8 v; } cv;
        #pragma unroll
        for (int jj = 0; jj < 4; jj++)
            cv.u4[jj] = feat32[(size_t)(quad * 4 + jj) * npts + pt];
        b[nt][0] = cv.v;
    }

    layer_fwd<1, 0 >(b, wf, wsB, 0, eb, lane, quad, srcA, srcB, mtbase);  // 32->128
    layer_fwd<4, 8 >(b, wf, wsB, 1, eb, lane, quad, srcA, srcB, mtbase);  // 128->128
    layer_fwd<4, 40>(b, wf, wsB, 2, eb, lane, quad, srcA, srcB, mtbase);  // 128->128
    layer_fwd<4, 72>(b, wf, wsB, 3, eb, lane, quad, srcA, srcB, mtbase);  // 128->128

    // ---- output layer: M=16 (4 real), mt=0 only, no ReLU ----
    f32x4 biaso = *(const f32x4*)&wsB[512 + quad * 4];
    f32x4 acco[2] = {biaso, biaso};
    #pragma unroll
    for (int kt = 0; kt < 4; kt++) {
        half8 w = wf[(size_t)(104 + kt) * 64 + lane];
        #pragma unroll
        for (int nt = 0; nt < 2; nt++)
            acco[nt] = __builtin_amdgcn_mfma_f32_16x16x32_f16(w, b[nt][kt], acco[nt], 0, 0, 0);
    }
    if (quad == 0) {
        #pragma unroll
        for (int nt = 0; nt < 2; nt++) {
            f32x4 v;
            #pragma unroll
            for (int r = 0; r < 4; r++) v[r] = acco[nt][r] * INV_SCALE;
            *(f32x4*)(out + (base + nt * 16 + col) * 4) = v;
        }
    }
}

// ---------------------------------------------------------------------------
// Fallback path (ws too small): R1-style fused kernel, unchanged.
// ---------------------------------------------------------------------------
template<int KT, int TOFF, bool RELU>
__device__ __forceinline__ void mlp_layer(_Float16* h, const half8* __restrict__ wf,
                                          const float* __restrict__ wsB, int layerIdx,
                                          int m0, int lane)
{
    const int col = lane & 15, quad = lane >> 4;
    const int sw = (col & 3) << 3;
    half8 a[2][KT];
    #pragma unroll
    for (int mt = 0; mt < 2; mt++)
        #pragma unroll
        for (int kt = 0; kt < KT; kt++)
            a[mt][kt] = *(const half8*)&h[(m0 + mt * 16 + col) * HSTRIDE + ((kt * 32 + quad * 8) ^ sw)];
    f32x4 acc[2][8];
    #pragma unroll
    for (int nt = 0; nt < 8; nt++) {
        float bv = wsB[layerIdx * 128 + nt * 16 + col];
        acc[0][nt] = (f32x4){bv, bv, bv, bv};
        acc[1][nt] = (f32x4){bv, bv, bv, bv};
    }
    #pragma unroll
    for (int nt = 0; nt < 8; nt++) {
        half8 b[KT];
        #pragma unroll
        for (int kt = 0; kt < KT; kt++)
            b[kt] = wf[(size_t)(TOFF + nt * KT + kt) * 64 + lane];
        #pragma unroll
        for (int mt = 0; mt < 2; mt++)
            #pragma unroll
            for (int kt = 0; kt < KT; kt++)
                acc[mt][nt] = __builtin_amdgcn_mfma_f32_16x16x32_f16(a[mt][kt], b[kt], acc[mt][nt], 0, 0, 0);
    }
    #pragma unroll
    for (int mt = 0; mt < 2; mt++)
        #pragma unroll
        for (int nt = 0; nt < 8; nt++) {
            f32x4 v = acc[mt][nt];
            #pragma unroll
            for (int r = 0; r < 4; r++) {
                float x = v[r];
                if (RELU) x = fmaxf(x, 0.0f);
                h[(m0 + mt * 16 + quad * 4 + r) * HSTRIDE + ((nt * 16 + col) ^ (r << 3))] = (_Float16)x;
            }
        }
}

__global__ __launch_bounds__(256, 2) void fused_kernel(
    const float* __restrict__ pos, const float* __restrict__ bmn, const float* __restrict__ bmx,
    const float* __restrict__ tables, const half8* __restrict__ wf, const float* __restrict__ wsB,
    float* __restrict__ out)
{
    __shared__ _Float16 hbuf[128 * HSTRIDE];
    __shared__ float outstage[512];
    const int t = threadIdx.x;
    const long base = (long)blockIdx.x * 128;
    {
        const int p = t >> 1, hh = t & 1;
        const long gp = base + p;
        const float b0x = bmn[0], b0y = bmn[1], b0z = bmn[2];
        const float nx = (pos[gp * 3 + 0] - b0x) / (bmx[0] - b0x);
        const float ny = (pos[gp * 3 + 1] - b0y) / (bmx[1] - b0y);
        const float nz = (pos[gp * 3 + 2] - b0z) / (bmx[2] - b0z);
        constexpr float RLO[8] = {16.f, 20.f, 25.f, 32.f, 40.f, 50.f, 64.f, 80.f};
        constexpr float RHI[8] = {101.f, 128.f, 161.f, 203.f, 256.f, 322.f, 406.f, 512.f};
        half8 fa, fb;
        #pragma unroll
        for (int li = 0; li < 8; li++) {
            const float res = hh ? RHI[li] : RLO[li];
            const float* tbl = tables + ((size_t)(hh * 8 + li) << 20);
            float xs = nx * res, ys = ny * res, zs = nz * res;
            float fx = floorf(xs), fy = floorf(ys), fz = floorf(zs);
            unsigned xi = (unsigned)fx, yi = (unsigned)fy, zi = (unsigned)fz;
            float tx = xs - fx, ty = ys - fy, tz = zs - fz;
            unsigned hx[2] = {xi, xi + 1u};
            unsigned hy[2] = {yi * 2654435761u, (yi + 1u) * 2654435761u};
            unsigned hz[2] = {zi * 805459861u, (zi + 1u) * 805459861u};
            float wx[2] = {1.0f - tx, tx}, wy[2] = {1.0f - ty, ty}, wz[2] = {1.0f - tz, tz};
            float a0 = 0.0f, a1 = 0.0f;
            #pragma unroll
            for (int c = 0; c < 8; c++) {
                unsigned hsh = hx[c & 1] ^ hy[(c >> 1) & 1] ^ hz[c >> 2];
                unsigned idx = hsh & TMASK;
                f32x2 f = *(const f32x2*)(tbl + (size_t)idx * 2);
                float w = wx[c & 1] * wy[(c >> 1) & 1] * wz[c >> 2];
                a0 += w * f.x;
                a1 += w * f.y;
            }
            if (li < 4) { fa[2 * li]       = (_Float16)(a0 * SCALE); fa[2 * li + 1]       = (_Float16)(a1 * SCALE); }
            else        { fb[2 * (li - 4)] = (_Float16)(a0 * SCALE); fb[2 * (li - 4) + 1] = (_Float16)(a1 * SCALE); }
        }
        const int sw = (p & 3) << 3;
        *(half8*)&hbuf[p * HSTRIDE + ((hh * 16) ^ sw)]       = fa;
        *(half8*)&hbuf[p * HSTRIDE + (((hh * 16) + 8) ^ sw)] = fb;
    }
    __syncthreads();
    {
        const int lane = t & 63;
        const int m0 = (t >> 6) * 32;
        mlp_layer<1, 0,   true>(hbuf, wf, wsB, 0, m0, lane);
        mlp_layer<4, 8,   true>(hbuf, wf, wsB, 1, m0, lane);
        mlp_layer<4, 40,  true>(hbuf, wf, wsB, 2, m0, lane);
        mlp_layer<4, 72,  true>(hbuf, wf, wsB, 3, m0, lane);
        const int col = lane & 15, quad = lane >> 4;
        const int sw = (col & 3) << 3;
        half8 a[2][4];
        #pragma unroll
        for (int mt = 0; mt < 2; mt++)
            #pragma unroll
            for (int kt = 0; kt < 4; kt++)
                a[mt][kt] = *(const half8*)&hbuf[(m0 + mt * 16 + col) * HSTRIDE + ((kt * 32 + quad * 8) ^ sw)];
        float bv = wsB[512 + col];
        f32x4 acc[2] = {(f32x4){bv, bv, bv, bv}, (f32x4){bv, bv, bv, bv}};
        #pragma unroll
        for (int kt = 0; kt < 4; kt++) {
            half8 bfr = wf[(size_t)(104 + kt) * 64 + lane];
            #pragma unroll
            for (int mt = 0; mt < 2; mt++)
                acc[mt] = __builtin_amdgcn_mfma_f32_16x16x32_f16(a[mt][kt], bfr, acc[mt], 0, 0, 0);
        }
        if (col < 4) {
            #pragma unroll
            for (int mt = 0; mt < 2; mt++)
                #pragma unroll
                for (int r = 0; r < 4; r++)
                    outstage[(m0 + mt * 16 + quad * 4 + r) * 4 + col] = acc[mt][r] * INV_SCALE;
        }
    }
    __syncthreads();
    if (t < 128) {
        f32x4 v = ((const f32x4*)outstage)[t];
        *(f32x4*)(out + (base + t) * 4) = v;
    }
}

extern "C" void kernel_launch(void* const* d_in, const int* in_sizes, int n_in,
                              void* d_out, int out_size, void* d_ws, size_t ws_size,
                              hipStream_t stream) {
    const float* pos    = (const float*)d_in[0];
    const float* bmn    = (const float*)d_in[1];
    const float* bmx    = (const float*)d_in[2];
    const float* tables = (const float*)d_in[3];
    const float* W0 = (const float*)d_in[4];
    const float* b0 = (const float*)d_in[5];
    const float* W1 = (const float*)d_in[6];
    const float* b1 = (const float*)d_in[7];
    const float* W2 = (const float*)d_in[8];
    const float* b2 = (const float*)d_in[9];
    const float* W3 = (const float*)d_in[10];
    const float* b3 = (const float*)d_in[11];
    const float* Wm = (const float*)d_in[12];
    const float* bm = (const float*)d_in[13];

    const int N = in_sizes[0] / 3;
    const size_t featBytes = (size_t)N * 16 * 4;          // [16][N] f16x2
    const size_t tabBytes  = (size_t)16 * 524288 * 2 * 2; // 32 MB f16
    const size_t need = featBytes + tabBytes + 110592 + 528 * 4;

    if (ws_size >= need && (N % 256) == 0) {
        _Float16* feat = (_Float16*)d_ws;
        _Float16* tabF = (_Float16*)((char*)d_ws + featBytes);
        _Float16* wsW  = (_Float16*)((char*)d_ws + featBytes + tabBytes);
        float*    wsB  = (float*)((char*)d_ws + featBytes + tabBytes + 110592);
        prep_kernel<<<16384 + 30, 256, 0, stream>>>(W0, W1, W2, W3, Wm, b0, b1, b2, b3, bm,
                                                    wsW, wsB, tables, tabF, 16384);
        encode_kernel<<<(N / 256) * 8, 256, 0, stream>>>(pos, bmn, bmx, tabF, feat, N);
        mlp_kernel<<<N / 128, 256, 0, stream>>>((const unsigned*)feat, (const half8*)wsW,
                                                wsB, (float*)d_out, N);
    } else {
        _Float16* wsW = (_Float16*)d_ws;
        float*    wsB = (float*)((char*)d_ws + 110592);
        prep_kernel<<<30, 256, 0, stream>>>(W0, W1, W2, W3, Wm, b0, b1, b2, b3, bm,
                                            wsW, wsB, tables, (_Float16*)nullptr, 0);
        fused_kernel<<<N / 128, 256, 0, stream>>>(pos, bmn, bmx, tables,
                                                  (const half8*)wsW, wsB, (float*)d_out);
    }
}

// Round 6
// 667.269 us; speedup vs baseline: 1.4864x; 1.4864x over previous
//
#include <hip/hip_runtime.h>

typedef _Float16 half8 __attribute__((ext_vector_type(8)));
typedef _Float16 half4 __attribute__((ext_vector_type(4)));
typedef _Float16 half2 __attribute__((ext_vector_type(2)));
typedef float    f32x4 __attribute__((ext_vector_type(4)));
typedef float    f32x2 __attribute__((ext_vector_type(2)));
typedef unsigned u32x2 __attribute__((ext_vector_type(2)));

#define TMASK ((1u << 19) - 1u)       // T = 2^19
#define HSTRIDE 136                    // fallback-kernel LDS stride
constexpr float SCALE = 65536.0f;      // activation scale: keeps f16 out of subnormal range
constexpr float INV_SCALE = 1.0f / 65536.0f;

// Dense-remap geometry for coarse levels 0..7 (s = res+2 guards x=1.0 edge)
__device__ __constant__ unsigned SC_TAB[8]  = {18, 22, 27, 34, 42, 52, 66, 82};
__device__ __constant__ unsigned DOFF_TAB[8] = {0, 5832, 16480, 36163, 75467, 149555, 290163, 577659};
#define DTOTAL 1129027u

// ---------------------------------------------------------------------------
// Prep: (a) fp32 FINE tables (levels 8-15) -> f16 pre-scaled, (b) weights ->
// fragment-native f16 layout + biases (unchanged from R4/R5).
// ---------------------------------------------------------------------------
__global__ void prep_kernel(const float* __restrict__ W0, const float* __restrict__ W1,
                            const float* __restrict__ W2, const float* __restrict__ W3,
                            const float* __restrict__ Wm,
                            const float* __restrict__ b0, const float* __restrict__ b1,
                            const float* __restrict__ b2, const float* __restrict__ b3,
                            const float* __restrict__ bm,
                            _Float16* __restrict__ wsW, float* __restrict__ wsB,
                            const float* __restrict__ tabSrc, _Float16* __restrict__ tabF,
                            int tabBlocks)
{
    if ((int)blockIdx.x < tabBlocks) {
        size_t i = (size_t)blockIdx.x * 256 + threadIdx.x;
        f32x4 v = ((const f32x4*)tabSrc)[i];
        half4 o;
        o[0] = (_Float16)(v.x * SCALE);
        o[1] = (_Float16)(v.y * SCALE);
        o[2] = (_Float16)(v.z * SCALE);
        o[3] = (_Float16)(v.w * SCALE);
        ((half4*)tabF)[i] = o;
        return;
    }
    int gid = ((int)blockIdx.x - tabBlocks) * 256 + threadIdx.x;
    if (gid < 6912) {                       // 108 tiles * 64 lanes
        int tile = gid >> 6, lane = gid & 63;
        const float* W; int K, N, toff;
        if (tile < 8)        { W = W0; K = 32;  N = 128; toff = 0;   }
        else if (tile < 40)  { W = W1; K = 128; N = 128; toff = 8;   }
        else if (tile < 72)  { W = W2; K = 128; N = 128; toff = 40;  }
        else if (tile < 104) { W = W3; K = 128; N = 128; toff = 72;  }
        else                 { W = Wm; K = 128; N = 4;   toff = 104; }
        int tt = tile - toff;
        int KT = K >> 5;
        int nt = tt / KT, kt = tt - nt * KT;
        int n = nt * 16 + (lane & 15);
        int kbase = kt * 32 + (lane >> 4) * 8;
        half8 v;
        #pragma unroll
        for (int j = 0; j < 8; j++) {
            int k = kbase + j;
            float w = (n < N) ? W[k * N + n] : 0.0f;
            v[j] = (_Float16)w;
        }
        *(half8*)(wsW + (size_t)gid * 8) = v;
    } else if (gid < 6912 + 528) {
        int i = gid - 6912;
        float v;
        if (i < 512) {
            int layer = i >> 7, n = i & 127;
            const float* b = (layer == 0) ? b0 : (layer == 1) ? b1 : (layer == 2) ? b2 : b3;
            v = b[n] * SCALE;
        } else {
            int n = i - 512;
            v = (n < 4) ? bm[n] * SCALE : 0.0f;
        }
        wsB[i] = v;
    }
}

// ---------------------------------------------------------------------------
// Dense remap build: dense[l][x + s*y + s*s*z] = f16(table[l][hash % T]).
// Bit-identical values to the hashed lookup; converts coarse-level random
// gathers into spatially-local dense gathers.
// ---------------------------------------------------------------------------
__global__ void dense_build(const float* __restrict__ tables, unsigned* __restrict__ dense)
{
    unsigned e = blockIdx.x * 256 + threadIdx.x;
    if (e >= DTOTAL) return;
    int l = 0;
    #pragma unroll
    for (int i = 1; i < 8; i++) l += (e >= DOFF_TAB[i]) ? 1 : 0;
    unsigned local = e - DOFF_TAB[l];
    unsigned s = SC_TAB[l];
    unsigned s2 = s * s;
    unsigned z = local / s2;
    unsigned rem = local - z * s2;
    unsigned y = rem / s;
    unsigned x = rem - y * s;
    unsigned h = (x ^ (y * 2654435761u) ^ (z * 805459861u)) & TMASK;
    const float* src = tables + ((size_t)l * 524288u + h) * 2;
    half2 o; o[0] = (_Float16)(src[0] * SCALE); o[1] = (_Float16)(src[1] * SCALE);
    union { half2 h2; unsigned u; } cv; cv.h2 = o;
    dense[e] = cv.u;
}

// ---------------------------------------------------------------------------
// Encode kernel. lvl0 = bid&7 pairs coarse l (dense remap) with fine l+8
// (hashed f16) on one XCD; hot set per XCD <= ~4.2 MB.
// Fine: R4's even/odd 8B slot trick, PLAIN loads (R5's nontemporal loads
// bypassed L2 -> 1.27GB refetch; reverted).
// Coarse: dense layout, 8 dword loads with 2x2x2 spatial locality ->
// L1-resident for l0-l2, high line reuse for l3-l7.
// ---------------------------------------------------------------------------
__global__ __launch_bounds__(256, 4) void encode_kernel(
    const float* __restrict__ pos, const float* __restrict__ bmn, const float* __restrict__ bmx,
    const _Float16* __restrict__ tabFine, const unsigned* __restrict__ dense,
    _Float16* __restrict__ feat, int npts)
{
    const int lvl0 = (int)(blockIdx.x & 7);
    const int p = (int)(blockIdx.x >> 3) * 256 + (int)threadIdx.x;
    const float bx = bmn[0], by = bmn[1], bz = bmn[2];
    const float nx = (pos[(size_t)p * 3 + 0] - bx) / (bmx[0] - bx);
    const float ny = (pos[(size_t)p * 3 + 1] - by) / (bmx[1] - by);
    const float nz = (pos[(size_t)p * 3 + 2] - bz) / (bmx[2] - bz);
    constexpr float RESL[16] = {16.f, 20.f, 25.f, 32.f, 40.f, 50.f, 64.f, 80.f,
                                101.f, 128.f, 161.f, 203.f, 256.f, 322.f, 406.f, 512.f};
    const int l0 = lvl0, l1 = lvl0 + 8;
    const _Float16* tblB = tabFine + ((size_t)lvl0 << 20);   // fine level l1 -> slot lvl0

    // ---- fine (hashed) indices ----
    unsigned idxBE[4], idxBO[4];
    bool oddB;
    float txB, tyB, tzB;
    {
        const float res = RESL[l1];
        float xs = nx * res, ys = ny * res, zs = nz * res;
        float fx = floorf(xs), fy = floorf(ys), fz = floorf(zs);
        unsigned xi = (unsigned)fx, yi = (unsigned)fy, zi = (unsigned)fz;
        txB = xs - fx; tyB = ys - fy; tzB = zs - fz;
        unsigned hy0 = yi * 2654435761u, hy1 = (yi + 1u) * 2654435761u;
        unsigned hz0 = zi * 805459861u,  hz1 = (zi + 1u) * 805459861u;
        unsigned hyz[4] = {hy0 ^ hz0, hy1 ^ hz0, hy0 ^ hz1, hy1 ^ hz1};
        unsigned e = (xi + 1u) & ~1u;
        unsigned o = xi | 1u;
        oddB = (xi & 1u) != 0u;
        #pragma unroll
        for (int g = 0; g < 4; g++) {
            idxBE[g] = (e ^ hyz[g]) & TMASK;
            idxBO[g] = (o ^ hyz[g]) & TMASK;
        }
    }

    // ---- issue fine slot loads (longest latency) first ----
    u32x2 sB[4];
    #pragma unroll
    for (int g = 0; g < 4; g++)
        sB[g] = *(const u32x2*)(tblB + (size_t)(idxBE[g] & ~1u) * 2);
    unsigned oBu[4];
    if (oddB) {
        #pragma unroll
        for (int g = 0; g < 4; g++)
            oBu[g] = *(const unsigned*)(tblB + (size_t)idxBO[g] * 2);
    }

    // ---- coarse (dense) indices + loads ----
    float txA, tyA, tzA;
    unsigned cl[4], ch[4];
    {
        const float res = RESL[l0];
        float xs = nx * res, ys = ny * res, zs = nz * res;
        float fx = floorf(xs), fy = floorf(ys), fz = floorf(zs);
        unsigned xi = (unsigned)fx, yi = (unsigned)fy, zi = (unsigned)fz;
        txA = xs - fx; tyA = ys - fy; tzA = zs - fz;
        const unsigned s = SC_TAB[l0];
        const unsigned s2 = s * s;
        const unsigned* dptr = dense + DOFF_TAB[l0];
        unsigned b00 = xi + s * yi + s2 * zi;
        unsigned bases[4] = {b00, b00 + s, b00 + s2, b00 + s2 + s};
        #pragma unroll
        for (int g = 0; g < 4; g++) {
            cl[g] = dptr[bases[g]];
            ch[g] = dptr[bases[g] + 1];
        }
    }

    // ---- trilinear weights ----
    float wyzA[4] = {(1.0f - tyA) * (1.0f - tzA), tyA * (1.0f - tzA),
                     (1.0f - tyA) * tzA,          tyA * tzA};
    float wyzB[4] = {(1.0f - tyB) * (1.0f - tzB), tyB * (1.0f - tzB),
                     (1.0f - tyB) * tzB,          tyB * tzB};

    // ---- coarse accumulate + store ----
    float a0 = 0.0f, a1 = 0.0f;
    #pragma unroll
    for (int g = 0; g < 4; g++) {
        union { unsigned u; half2 h; } lo, hi;
        lo.u = cl[g]; hi.u = ch[g];
        float w0 = wyzA[g] * (1.0f - txA), w1 = wyzA[g] * txA;
        a0 += w0 * (float)lo.h[0] + w1 * (float)hi.h[0];
        a1 += w0 * (float)lo.h[1] + w1 * (float)hi.h[1];
    }
    {
        half2 ov; ov[0] = (_Float16)a0; ov[1] = (_Float16)a1;
        union { half2 h; unsigned u; } cv; cv.h = ov;
        __builtin_nontemporal_store(cv.u, (unsigned*)(feat + ((size_t)l0 * npts + p) * 2));
    }

    // ---- fine accumulate + store ----
    float b0 = 0.0f, b1 = 0.0f;
    #pragma unroll
    for (int g = 0; g < 4; g++) {
        union { unsigned u; half2 h; } lo, hi, ov;
        lo.u = sB[g][0]; hi.u = sB[g][1];
        bool pe = (idxBE[g] & 1u) != 0u;
        half2 fe  = pe ? hi.h : lo.h;
        half2 fe1 = pe ? lo.h : hi.h;
        ov.u = oddB ? oBu[g] : 0u;
        half2 fx0 = oddB ? ov.h : fe;
        half2 fx1 = oddB ? fe : fe1;
        float w0 = wyzB[g] * (1.0f - txB), w1 = wyzB[g] * txB;
        b0 += w0 * (float)fx0[0] + w1 * (float)fx1[0];
        b1 += w0 * (float)fx0[1] + w1 * (float)fx1[1];
    }
    {
        half2 ov; ov[0] = (_Float16)b0; ov[1] = (_Float16)b1;
        union { half2 h; unsigned u; } cv; cv.h = ov;
        __builtin_nontemporal_store(cv.u, (unsigned*)(feat + ((size_t)l1 * npts + p) * 2));
    }
}

// ---------------------------------------------------------------------------
// MLP kernel (R5 role-swapped): D = W(A-frag) x act(B-frag), wave-private
// D->B transform via 16 ds_write_b64 + 16 ds_read_b64, NO barriers.
// ---------------------------------------------------------------------------
#define ELANE 34   // dwords per lane in exchange buffer

template<int KT, int TOFF>
__device__ __forceinline__ void layer_fwd(half8 b[2][4], const half8* __restrict__ wf,
                                          const float* __restrict__ wsB, int li,
                                          unsigned* __restrict__ eb, int lane, int quad,
                                          unsigned srcA, unsigned srcB, int mtbase)
{
    f32x4 acc[8][2];
    #pragma unroll
    for (int mt = 0; mt < 8; mt++) {
        f32x4 bias = *(const f32x4*)&wsB[li * 128 + mt * 16 + quad * 4];
        half8 w[KT];
        #pragma unroll
        for (int kt = 0; kt < KT; kt++)
            w[kt] = wf[(size_t)(TOFF + mt * KT + kt) * 64 + lane];
        acc[mt][0] = bias;
        acc[mt][1] = bias;
        #pragma unroll
        for (int nt = 0; nt < 2; nt++)
            #pragma unroll
            for (int kt = 0; kt < KT; kt++)
                acc[mt][nt] = __builtin_amdgcn_mfma_f32_16x16x32_f16(w[kt], b[nt][kt], acc[mt][nt], 0, 0, 0);
    }
    unsigned* wptr = eb + lane * ELANE;
    #pragma unroll
    for (int mt = 0; mt < 8; mt++)
        #pragma unroll
        for (int nt = 0; nt < 2; nt++) {
            union { _Float16 h[4]; unsigned long long u64; } pk;
            #pragma unroll
            for (int r = 0; r < 4; r++)
                pk.h[r] = (_Float16)fmaxf(acc[mt][nt][r], 0.0f);
            *(unsigned long long*)(wptr + (mt * 2 + nt) * 2) = pk.u64;
        }
    #pragma unroll
    for (int nt = 0; nt < 2; nt++)
        #pragma unroll
        for (int ktp = 0; ktp < 4; ktp++) {
            int mt = 2 * ktp + mtbase;
            union { unsigned long long u64[2]; half8 v; } cv;
            cv.u64[0] = *(const unsigned long long*)(eb + srcA * ELANE + (mt * 2 + nt) * 2);
            cv.u64[1] = *(const unsigned long long*)(eb + srcB * ELANE + (mt * 2 + nt) * 2);
            b[nt][ktp] = cv.v;
        }
}

__global__ __launch_bounds__(256) void mlp_kernel(
    const unsigned* __restrict__ feat32, const half8* __restrict__ wf,
    const float* __restrict__ wsB, float* __restrict__ out, int npts)
{
    __shared__ unsigned ebuf[4 * 64 * ELANE];
    const int t = threadIdx.x;
    const int lane = t & 63, wv = t >> 6;
    const int col = lane & 15, quad = lane >> 4;
    const long base = (long)blockIdx.x * 128 + wv * 32;
    unsigned* eb = ebuf + wv * (64 * ELANE);
    const int q1 = 2 * (quad & 1);
    const unsigned srcA = (unsigned)(col + 16 * q1);
    const unsigned srcB = (unsigned)(col + 16 * (q1 + 1));
    const int mtbase = quad >> 1;

    half8 b[2][4];
    #pragma unroll
    for (int nt = 0; nt < 2; nt++) {
        const long pt = base + nt * 16 + col;
        union { unsigned u4[4]; half8 v; } cv;
        #pragma unroll
        for (int jj = 0; jj < 4; jj++)
            cv.u4[jj] = feat32[(size_t)(quad * 4 + jj) * npts + pt];
        b[nt][0] = cv.v;
    }

    layer_fwd<1, 0 >(b, wf, wsB, 0, eb, lane, quad, srcA, srcB, mtbase);  // 32->128
    layer_fwd<4, 8 >(b, wf, wsB, 1, eb, lane, quad, srcA, srcB, mtbase);  // 128->128
    layer_fwd<4, 40>(b, wf, wsB, 2, eb, lane, quad, srcA, srcB, mtbase);  // 128->128
    layer_fwd<4, 72>(b, wf, wsB, 3, eb, lane, quad, srcA, srcB, mtbase);  // 128->128

    f32x4 biaso = *(const f32x4*)&wsB[512 + quad * 4];
    f32x4 acco[2] = {biaso, biaso};
    #pragma unroll
    for (int kt = 0; kt < 4; kt++) {
        half8 w = wf[(size_t)(104 + kt) * 64 + lane];
        #pragma unroll
        for (int nt = 0; nt < 2; nt++)
            acco[nt] = __builtin_amdgcn_mfma_f32_16x16x32_f16(w, b[nt][kt], acco[nt], 0, 0, 0);
    }
    if (quad == 0) {
        #pragma unroll
        for (int nt = 0; nt < 2; nt++) {
            f32x4 v;
            #pragma unroll
            for (int r = 0; r < 4; r++) v[r] = acco[nt][r] * INV_SCALE;
            *(f32x4*)(out + (base + nt * 16 + col) * 4) = v;
        }
    }
}

// ---------------------------------------------------------------------------
// Fallback path (ws too small): R1-style fused kernel, unchanged.
// ---------------------------------------------------------------------------
template<int KT, int TOFF, bool RELU>
__device__ __forceinline__ void mlp_layer(_Float16* h, const half8* __restrict__ wf,
                                          const float* __restrict__ wsB, int layerIdx,
                                          int m0, int lane)
{
    const int col = lane & 15, quad = lane >> 4;
    const int sw = (col & 3) << 3;
    half8 a[2][KT];
    #pragma unroll
    for (int mt = 0; mt < 2; mt++)
        #pragma unroll
        for (int kt = 0; kt < KT; kt++)
            a[mt][kt] = *(const half8*)&h[(m0 + mt * 16 + col) * HSTRIDE + ((kt * 32 + quad * 8) ^ sw)];
    f32x4 acc[2][8];
    #pragma unroll
    for (int nt = 0; nt < 8; nt++) {
        float bv = wsB[layerIdx * 128 + nt * 16 + col];
        acc[0][nt] = (f32x4){bv, bv, bv, bv};
        acc[1][nt] = (f32x4){bv, bv, bv, bv};
    }
    #pragma unroll
    for (int nt = 0; nt < 8; nt++) {
        half8 b[KT];
        #pragma unroll
        for (int kt = 0; kt < KT; kt++)
            b[kt] = wf[(size_t)(TOFF + nt * KT + kt) * 64 + lane];
        #pragma unroll
        for (int mt = 0; mt < 2; mt++)
            #pragma unroll
            for (int kt = 0; kt < KT; kt++)
                acc[mt][nt] = __builtin_amdgcn_mfma_f32_16x16x32_f16(a[mt][kt], b[kt], acc[mt][nt], 0, 0, 0);
    }
    #pragma unroll
    for (int mt = 0; mt < 2; mt++)
        #pragma unroll
        for (int nt = 0; nt < 8; nt++) {
            f32x4 v = acc[mt][nt];
            #pragma unroll
            for (int r = 0; r < 4; r++) {
                float x = v[r];
                if (RELU) x = fmaxf(x, 0.0f);
                h[(m0 + mt * 16 + quad * 4 + r) * HSTRIDE + ((nt * 16 + col) ^ (r << 3))] = (_Float16)x;
            }
        }
}

__global__ __launch_bounds__(256, 2) void fused_kernel(
    const float* __restrict__ pos, const float* __restrict__ bmn, const float* __restrict__ bmx,
    const float* __restrict__ tables, const half8* __restrict__ wf, const float* __restrict__ wsB,
    float* __restrict__ out)
{
    __shared__ _Float16 hbuf[128 * HSTRIDE];
    __shared__ float outstage[512];
    const int t = threadIdx.x;
    const long base = (long)blockIdx.x * 128;
    {
        const int p = t >> 1, hh = t & 1;
        const long gp = base + p;
        const float b0x = bmn[0], b0y = bmn[1], b0z = bmn[2];
        const float nx = (pos[gp * 3 + 0] - b0x) / (bmx[0] - b0x);
        const float ny = (pos[gp * 3 + 1] - b0y) / (bmx[1] - b0y);
        const float nz = (pos[gp * 3 + 2] - b0z) / (bmx[2] - b0z);
        constexpr float RLO[8] = {16.f, 20.f, 25.f, 32.f, 40.f, 50.f, 64.f, 80.f};
        constexpr float RHI[8] = {101.f, 128.f, 161.f, 203.f, 256.f, 322.f, 406.f, 512.f};
        half8 fa, fb;
        #pragma unroll
        for (int li = 0; li < 8; li++) {
            const float res = hh ? RHI[li] : RLO[li];
            const float* tbl = tables + ((size_t)(hh * 8 + li) << 20);
            float xs = nx * res, ys = ny * res, zs = nz * res;
            float fx = floorf(xs), fy = floorf(ys), fz = floorf(zs);
            unsigned xi = (unsigned)fx, yi = (unsigned)fy, zi = (unsigned)fz;
            float tx = xs - fx, ty = ys - fy, tz = zs - fz;
            unsigned hx[2] = {xi, xi + 1u};
            unsigned hy[2] = {yi * 2654435761u, (yi + 1u) * 2654435761u};
            unsigned hz[2] = {zi * 805459861u, (zi + 1u) * 805459861u};
            float wx[2] = {1.0f - tx, tx}, wy[2] = {1.0f - ty, ty}, wz[2] = {1.0f - tz, tz};
            float a0 = 0.0f, a1 = 0.0f;
            #pragma unroll
            for (int c = 0; c < 8; c++) {
                unsigned hsh = hx[c & 1] ^ hy[(c >> 1) & 1] ^ hz[c >> 2];
                unsigned idx = hsh & TMASK;
                f32x2 f = *(const f32x2*)(tbl + (size_t)idx * 2);
                float w = wx[c & 1] * wy[(c >> 1) & 1] * wz[c >> 2];
                a0 += w * f.x;
                a1 += w * f.y;
            }
            if (li < 4) { fa[2 * li]       = (_Float16)(a0 * SCALE); fa[2 * li + 1]       = (_Float16)(a1 * SCALE); }
            else        { fb[2 * (li - 4)] = (_Float16)(a0 * SCALE); fb[2 * (li - 4) + 1] = (_Float16)(a1 * SCALE); }
        }
        const int sw = (p & 3) << 3;
        *(half8*)&hbuf[p * HSTRIDE + ((hh * 16) ^ sw)]       = fa;
        *(half8*)&hbuf[p * HSTRIDE + (((hh * 16) + 8) ^ sw)] = fb;
    }
    __syncthreads();
    {
        const int lane = t & 63;
        const int m0 = (t >> 6) * 32;
        mlp_layer<1, 0,   true>(hbuf, wf, wsB, 0, m0, lane);
        mlp_layer<4, 8,   true>(hbuf, wf, wsB, 1, m0, lane);
        mlp_layer<4, 40,  true>(hbuf, wf, wsB, 2, m0, lane);
        mlp_layer<4, 72,  true>(hbuf, wf, wsB, 3, m0, lane);
        const int col = lane & 15, quad = lane >> 4;
        const int sw = (col & 3) << 3;
        half8 a[2][4];
        #pragma unroll
        for (int mt = 0; mt < 2; mt++)
            #pragma unroll
            for (int kt = 0; kt < 4; kt++)
                a[mt][kt] = *(const half8*)&hbuf[(m0 + mt * 16 + col) * HSTRIDE + ((kt * 32 + quad * 8) ^ sw)];
        float bv = wsB[512 + col];
        f32x4 acc[2] = {(f32x4){bv, bv, bv, bv}, (f32x4){bv, bv, bv, bv}};
        #pragma unroll
        for (int kt = 0; kt < 4; kt++) {
            half8 bfr = wf[(size_t)(104 + kt) * 64 + lane];
            #pragma unroll
            for (int mt = 0; mt < 2; mt++)
                acc[mt] = __builtin_amdgcn_mfma_f32_16x16x32_f16(a[mt][kt], bfr, acc[mt], 0, 0, 0);
        }
        if (col < 4) {
            #pragma unroll
            for (int mt = 0; mt < 2; mt++)
                #pragma unroll
                for (int r = 0; r < 4; r++)
                    outstage[(m0 + mt * 16 + quad * 4 + r) * 4 + col] = acc[mt][r] * INV_SCALE;
        }
    }
    __syncthreads();
    if (t < 128) {
        f32x4 v = ((const f32x4*)outstage)[t];
        *(f32x4*)(out + (base + t) * 4) = v;
    }
}

extern "C" void kernel_launch(void* const* d_in, const int* in_sizes, int n_in,
                              void* d_out, int out_size, void* d_ws, size_t ws_size,
                              hipStream_t stream) {
    const float* pos    = (const float*)d_in[0];
    const float* bmn    = (const float*)d_in[1];
    const float* bmx    = (const float*)d_in[2];
    const float* tables = (const float*)d_in[3];
    const float* W0 = (const float*)d_in[4];
    const float* b0 = (const float*)d_in[5];
    const float* W1 = (const float*)d_in[6];
    const float* b1 = (const float*)d_in[7];
    const float* W2 = (const float*)d_in[8];
    const float* b2 = (const float*)d_in[9];
    const float* W3 = (const float*)d_in[10];
    const float* b3 = (const float*)d_in[11];
    const float* Wm = (const float*)d_in[12];
    const float* bm = (const float*)d_in[13];

    const int N = in_sizes[0] / 3;
    const size_t featBytes    = (size_t)N * 16 * 4;             // [16][N] f16x2
    const size_t tabFineBytes = (size_t)8 * 524288 * 2 * 2;     // 16 MB f16, levels 8-15
    const size_t denseBytes   = ((size_t)DTOTAL * 4 + 255) & ~(size_t)255;  // ~4.5 MB
    const size_t need = featBytes + tabFineBytes + denseBytes + 110592 + 2112;

    if (ws_size >= need && (N % 256) == 0) {
        _Float16* feat  = (_Float16*)d_ws;
        _Float16* tabF  = (_Float16*)((char*)d_ws + featBytes);
        unsigned* dense = (unsigned*)((char*)d_ws + featBytes + tabFineBytes);
        _Float16* wsW   = (_Float16*)((char*)d_ws + featBytes + tabFineBytes + denseBytes);
        float*    wsB   = (float*)((char*)d_ws + featBytes + tabFineBytes + denseBytes + 110592);
        // fine-table f16 conversion: 8 levels * T * 2 floats = 8.39M floats
        prep_kernel<<<8192 + 30, 256, 0, stream>>>(W0, W1, W2, W3, Wm, b0, b1, b2, b3, bm,
                                                   wsW, wsB, tables + (size_t)8 * 524288 * 2,
                                                   tabF, 8192);
        dense_build<<<(DTOTAL + 255) / 256, 256, 0, stream>>>(tables, dense);
        encode_kernel<<<(N / 256) * 8, 256, 0, stream>>>(pos, bmn, bmx, tabF, dense, feat, N);
        mlp_kernel<<<N / 128, 256, 0, stream>>>((const unsigned*)feat, (const half8*)wsW,
                                                wsB, (float*)d_out, N);
    } else {
        _Float16* wsW = (_Float16*)d_ws;
        float*    wsB = (float*)((char*)d_ws + 110592);
        prep_kernel<<<30, 256, 0, stream>>>(W0, W1, W2, W3, Wm, b0, b1, b2, b3, bm,
                                            wsW, wsB, tables, (_Float16*)nullptr, 0);
        fused_kernel<<<N / 128, 256, 0, stream>>>(pos, bmn, bmx, tables,
                                                  (const half8*)wsW, wsB, (float*)d_out);
    }
}

// Round 7
// 622.084 us; speedup vs baseline: 1.5944x; 1.0726x over previous
//
#include <hip/hip_runtime.h>

typedef _Float16 half8 __attribute__((ext_vector_type(8)));
typedef _Float16 half4 __attribute__((ext_vector_type(4)));
typedef _Float16 half2 __attribute__((ext_vector_type(2)));
typedef float    f32x4 __attribute__((ext_vector_type(4)));
typedef float    f32x2 __attribute__((ext_vector_type(2)));
typedef unsigned u32x2 __attribute__((ext_vector_type(2)));
typedef unsigned u32x4 __attribute__((ext_vector_type(4)));

#define TMASK ((1u << 19) - 1u)       // T = 2^19
#define HSTRIDE 136                    // fallback-kernel LDS stride
constexpr float SCALE = 65536.0f;      // activation scale: keeps f16 out of subnormal range
constexpr float INV_SCALE = 1.0f / 65536.0f;

// Dense-remap geometry for coarse levels 0..7 (s = res+2 guards x=1.0 edge)
__device__ __constant__ unsigned SC_TAB[8]  = {18, 22, 27, 34, 42, 52, 66, 82};
__device__ __constant__ unsigned DOFF_TAB[8] = {0, 5832, 16480, 36163, 75467, 149555, 290163, 577659};
#define DTOTAL 1129027u

// ---------------------------------------------------------------------------
// Prep: (a) fp32 FINE tables (levels 8-15) -> f16 pre-scaled, (b) weights ->
// fragment-native f16 layout + biases.
// ---------------------------------------------------------------------------
__global__ void prep_kernel(const float* __restrict__ W0, const float* __restrict__ W1,
                            const float* __restrict__ W2, const float* __restrict__ W3,
                            const float* __restrict__ Wm,
                            const float* __restrict__ b0, const float* __restrict__ b1,
                            const float* __restrict__ b2, const float* __restrict__ b3,
                            const float* __restrict__ bm,
                            _Float16* __restrict__ wsW, float* __restrict__ wsB,
                            const float* __restrict__ tabSrc, _Float16* __restrict__ tabF,
                            int tabBlocks)
{
    if ((int)blockIdx.x < tabBlocks) {
        size_t i = (size_t)blockIdx.x * 256 + threadIdx.x;
        f32x4 v = ((const f32x4*)tabSrc)[i];
        half4 o;
        o[0] = (_Float16)(v.x * SCALE);
        o[1] = (_Float16)(v.y * SCALE);
        o[2] = (_Float16)(v.z * SCALE);
        o[3] = (_Float16)(v.w * SCALE);
        ((half4*)tabF)[i] = o;
        return;
    }
    int gid = ((int)blockIdx.x - tabBlocks) * 256 + threadIdx.x;
    if (gid < 6912) {                       // 108 tiles * 64 lanes
        int tile = gid >> 6, lane = gid & 63;
        const float* W; int K, N, toff;
        if (tile < 8)        { W = W0; K = 32;  N = 128; toff = 0;   }
        else if (tile < 40)  { W = W1; K = 128; N = 128; toff = 8;   }
        else if (tile < 72)  { W = W2; K = 128; N = 128; toff = 40;  }
        else if (tile < 104) { W = W3; K = 128; N = 128; toff = 72;  }
        else                 { W = Wm; K = 128; N = 4;   toff = 104; }
        int tt = tile - toff;
        int KT = K >> 5;
        int nt = tt / KT, kt = tt - nt * KT;
        int n = nt * 16 + (lane & 15);
        int kbase = kt * 32 + (lane >> 4) * 8;
        half8 v;
        #pragma unroll
        for (int j = 0; j < 8; j++) {
            int k = kbase + j;
            float w = (n < N) ? W[k * N + n] : 0.0f;
            v[j] = (_Float16)w;
        }
        *(half8*)(wsW + (size_t)gid * 8) = v;
    } else if (gid < 6912 + 528) {
        int i = gid - 6912;
        float v;
        if (i < 512) {
            int layer = i >> 7, n = i & 127;
            const float* b = (layer == 0) ? b0 : (layer == 1) ? b1 : (layer == 2) ? b2 : b3;
            v = b[n] * SCALE;
        } else {
            int n = i - 512;
            v = (n < 4) ? bm[n] * SCALE : 0.0f;
        }
        wsB[i] = v;
    }
}

// ---------------------------------------------------------------------------
// Dense remap build: dense[l][x + s*y + s*s*z] = f16(table[l][hash % T]).
// ---------------------------------------------------------------------------
__global__ void dense_build(const float* __restrict__ tables, unsigned* __restrict__ dense)
{
    unsigned e = blockIdx.x * 256 + threadIdx.x;
    if (e >= DTOTAL) return;
    int l = 0;
    #pragma unroll
    for (int i = 1; i < 8; i++) l += (e >= DOFF_TAB[i]) ? 1 : 0;
    unsigned local = e - DOFF_TAB[l];
    unsigned s = SC_TAB[l];
    unsigned s2 = s * s;
    unsigned z = local / s2;
    unsigned rem = local - z * s2;
    unsigned y = rem / s;
    unsigned x = rem - y * s;
    unsigned h = (x ^ (y * 2654435761u) ^ (z * 805459861u)) & TMASK;
    const float* src = tables + ((size_t)l * 524288u + h) * 2;
    half2 o; o[0] = (_Float16)(src[0] * SCALE); o[1] = (_Float16)(src[1] * SCALE);
    union { half2 h2; unsigned u; } cv; cv.h2 = o;
    dense[e] = cv.u;
}

// ---------------------------------------------------------------------------
// Encode kernel (unchanged from R6): lvl0 = bid&7 pairs coarse l (dense) with
// fine l+8 (hashed f16, even/odd 8B-slot trick) on one XCD.
// ---------------------------------------------------------------------------
__global__ __launch_bounds__(256, 4) void encode_kernel(
    const float* __restrict__ pos, const float* __restrict__ bmn, const float* __restrict__ bmx,
    const _Float16* __restrict__ tabFine, const unsigned* __restrict__ dense,
    _Float16* __restrict__ feat, int npts)
{
    const int lvl0 = (int)(blockIdx.x & 7);
    const int p = (int)(blockIdx.x >> 3) * 256 + (int)threadIdx.x;
    const float bx = bmn[0], by = bmn[1], bz = bmn[2];
    const float nx = (pos[(size_t)p * 3 + 0] - bx) / (bmx[0] - bx);
    const float ny = (pos[(size_t)p * 3 + 1] - by) / (bmx[1] - by);
    const float nz = (pos[(size_t)p * 3 + 2] - bz) / (bmx[2] - bz);
    constexpr float RESL[16] = {16.f, 20.f, 25.f, 32.f, 40.f, 50.f, 64.f, 80.f,
                                101.f, 128.f, 161.f, 203.f, 256.f, 322.f, 406.f, 512.f};
    const int l0 = lvl0, l1 = lvl0 + 8;
    const _Float16* tblB = tabFine + ((size_t)lvl0 << 20);

    unsigned idxBE[4], idxBO[4];
    bool oddB;
    float txB, tyB, tzB;
    {
        const float res = RESL[l1];
        float xs = nx * res, ys = ny * res, zs = nz * res;
        float fx = floorf(xs), fy = floorf(ys), fz = floorf(zs);
        unsigned xi = (unsigned)fx, yi = (unsigned)fy, zi = (unsigned)fz;
        txB = xs - fx; tyB = ys - fy; tzB = zs - fz;
        unsigned hy0 = yi * 2654435761u, hy1 = (yi + 1u) * 2654435761u;
        unsigned hz0 = zi * 805459861u,  hz1 = (zi + 1u) * 805459861u;
        unsigned hyz[4] = {hy0 ^ hz0, hy1 ^ hz0, hy0 ^ hz1, hy1 ^ hz1};
        unsigned e = (xi + 1u) & ~1u;
        unsigned o = xi | 1u;
        oddB = (xi & 1u) != 0u;
        #pragma unroll
        for (int g = 0; g < 4; g++) {
            idxBE[g] = (e ^ hyz[g]) & TMASK;
            idxBO[g] = (o ^ hyz[g]) & TMASK;
        }
    }

    u32x2 sB[4];
    #pragma unroll
    for (int g = 0; g < 4; g++)
        sB[g] = *(const u32x2*)(tblB + (size_t)(idxBE[g] & ~1u) * 2);
    unsigned oBu[4];
    if (oddB) {
        #pragma unroll
        for (int g = 0; g < 4; g++)
            oBu[g] = *(const unsigned*)(tblB + (size_t)idxBO[g] * 2);
    }

    float txA, tyA, tzA;
    unsigned cl[4], ch[4];
    {
        const float res = RESL[l0];
        float xs = nx * res, ys = ny * res, zs = nz * res;
        float fx = floorf(xs), fy = floorf(ys), fz = floorf(zs);
        unsigned xi = (unsigned)fx, yi = (unsigned)fy, zi = (unsigned)fz;
        txA = xs - fx; tyA = ys - fy; tzA = zs - fz;
        const unsigned s = SC_TAB[l0];
        const unsigned s2 = s * s;
        const unsigned* dptr = dense + DOFF_TAB[l0];
        unsigned b00 = xi + s * yi + s2 * zi;
        unsigned bases[4] = {b00, b00 + s, b00 + s2, b00 + s2 + s};
        #pragma unroll
        for (int g = 0; g < 4; g++) {
            cl[g] = dptr[bases[g]];
            ch[g] = dptr[bases[g] + 1];
        }
    }

    float wyzA[4] = {(1.0f - tyA) * (1.0f - tzA), tyA * (1.0f - tzA),
                     (1.0f - tyA) * tzA,          tyA * tzA};
    float wyzB[4] = {(1.0f - tyB) * (1.0f - tzB), tyB * (1.0f - tzB),
                     (1.0f - tyB) * tzB,          tyB * tzB};

    float a0 = 0.0f, a1 = 0.0f;
    #pragma unroll
    for (int g = 0; g < 4; g++) {
        union { unsigned u; half2 h; } lo, hi;
        lo.u = cl[g]; hi.u = ch[g];
        float w0 = wyzA[g] * (1.0f - txA), w1 = wyzA[g] * txA;
        a0 += w0 * (float)lo.h[0] + w1 * (float)hi.h[0];
        a1 += w0 * (float)lo.h[1] + w1 * (float)hi.h[1];
    }
    {
        half2 ov; ov[0] = (_Float16)a0; ov[1] = (_Float16)a1;
        union { half2 h; unsigned u; } cv; cv.h = ov;
        __builtin_nontemporal_store(cv.u, (unsigned*)(feat + ((size_t)l0 * npts + p) * 2));
    }

    float b0 = 0.0f, b1 = 0.0f;
    #pragma unroll
    for (int g = 0; g < 4; g++) {
        union { unsigned u; half2 h; } lo, hi, ov;
        lo.u = sB[g][0]; hi.u = sB[g][1];
        bool pe = (idxBE[g] & 1u) != 0u;
        half2 fe  = pe ? hi.h : lo.h;
        half2 fe1 = pe ? lo.h : hi.h;
        ov.u = oddB ? oBu[g] : 0u;
        half2 fx0 = oddB ? ov.h : fe;
        half2 fx1 = oddB ? fe : fe1;
        float w0 = wyzB[g] * (1.0f - txB), w1 = wyzB[g] * txB;
        b0 += w0 * (float)fx0[0] + w1 * (float)fx1[0];
        b1 += w0 * (float)fx0[1] + w1 * (float)fx1[1];
    }
    {
        half2 ov; ov[0] = (_Float16)b0; ov[1] = (_Float16)b1;
        union { half2 h; unsigned u; } cv; cv.h = ov;
        __builtin_nontemporal_store(cv.u, (unsigned*)(feat + ((size_t)l1 * npts + p) * 2));
    }
}

// ---------------------------------------------------------------------------
// MLP kernel, R7: role-swapped MFMA with 64 points/wave (nt=4).
//   A-frag (weights): m=lane&15 -> outchan, k=quad*8+j -> inchan.
//   B-frag (act):     n=lane&15 -> point,   k=quad*8+j -> inchan.
//   D:                col=lane&15 -> point, row=quad*4+r -> outchan.
// Per-mt immediate publish keeps acc live at 16 VGPRs. Exchange is
// 16 ds_write_b128 + 16 ds_read_b128 per layer, wave-private, NO barriers.
// Lane permutation identical to validated R5: srcA/srcB/mtbase; nt extends
// trivially (point id preserved per nt-tile).
// ---------------------------------------------------------------------------
#define ELANE 68   // dwords per lane: 64 payload + 4 pad; 272B (16B-aligned)

template<int KT, int TOFF>
__device__ __forceinline__ void layer_fwd4(half8 b[4][4], const half8* __restrict__ wf,
                                           const float* __restrict__ wsB, int li,
                                           unsigned* __restrict__ eb, int lane, int quad,
                                           unsigned srcA, unsigned srcB, int mtbase)
{
    unsigned* wptr = eb + lane * ELANE;
    #pragma unroll
    for (int mt = 0; mt < 8; mt++) {
        f32x4 bias = *(const f32x4*)&wsB[li * 128 + mt * 16 + quad * 4];
        half8 w[KT];
        #pragma unroll
        for (int kt = 0; kt < KT; kt++)
            w[kt] = wf[(size_t)(TOFF + mt * KT + kt) * 64 + lane];
        f32x4 acc[4] = {bias, bias, bias, bias};
        #pragma unroll
        for (int nt = 0; nt < 4; nt++)
            #pragma unroll
            for (int kt = 0; kt < KT; kt++)
                acc[nt] = __builtin_amdgcn_mfma_f32_16x16x32_f16(w[kt], b[nt][kt], acc[nt], 0, 0, 0);
        // publish this mt immediately: 2 x ds_write_b128 (nt pairs)
        #pragma unroll
        for (int np = 0; np < 2; np++) {
            union { _Float16 h[8]; u32x4 v; } pk;
            #pragma unroll
            for (int r = 0; r < 4; r++) {
                pk.h[r]     = (_Float16)fmaxf(acc[2 * np][r],     0.0f);
                pk.h[4 + r] = (_Float16)fmaxf(acc[2 * np + 1][r], 0.0f);
            }
            *(u32x4*)(wptr + mt * 8 + np * 4) = pk.v;
        }
    }
    // gather next-layer B-frags: 16 x ds_read_b128; same-wave program order
    // guarantees write->read visibility without a barrier.
    #pragma unroll
    for (int ktp = 0; ktp < 4; ktp++) {
        int mt = 2 * ktp + mtbase;
        u32x4 rA0 = *(const u32x4*)(eb + srcA * ELANE + mt * 8);
        u32x4 rA1 = *(const u32x4*)(eb + srcA * ELANE + mt * 8 + 4);
        u32x4 rB0 = *(const u32x4*)(eb + srcB * ELANE + mt * 8);
        u32x4 rB1 = *(const u32x4*)(eb + srcB * ELANE + mt * 8 + 4);
        union { u32x4 v; half8 h; } c0, c1, c2, c3;
        c0.v = (u32x4){rA0[0], rA0[1], rB0[0], rB0[1]};
        c1.v = (u32x4){rA0[2], rA0[3], rB0[2], rB0[3]};
        c2.v = (u32x4){rA1[0], rA1[1], rB1[0], rB1[1]};
        c3.v = (u32x4){rA1[2], rA1[3], rB1[2], rB1[3]};
        b[0][ktp] = c0.h;
        b[1][ktp] = c1.h;
        b[2][ktp] = c2.h;
        b[3][ktp] = c3.h;
    }
}

__global__ __launch_bounds__(256) void mlp_kernel(
    const unsigned* __restrict__ feat32, const half8* __restrict__ wf,
    const float* __restrict__ wsB, float* __restrict__ out, int npts)
{
    __shared__ __align__(16) unsigned ebuf[4 * 64 * ELANE];
    const int t = threadIdx.x;
    const int lane = t & 63, wv = t >> 6;
    const int col = lane & 15, quad = lane >> 4;
    const long base = (long)blockIdx.x * 256 + wv * 64;
    unsigned* eb = ebuf + wv * (64 * ELANE);
    const int q1 = 2 * (quad & 1);
    const unsigned srcA = (unsigned)(col + 16 * q1);
    const unsigned srcB = (unsigned)(col + 16 * (q1 + 1));
    const int mtbase = quad >> 1;

    // ---- layer-0 B-frags straight from feat (chan-major, coalesced) ----
    half8 b[4][4];
    #pragma unroll
    for (int nt = 0; nt < 4; nt++) {
        const long pt = base + nt * 16 + col;
        union { unsigned u4[4]; half8 v; } cv;
        #pragma unroll
        for (int jj = 0; jj < 4; jj++)
            cv.u4[jj] = feat32[(size_t)(quad * 4 + jj) * npts + pt];
        b[nt][0] = cv.v;
    }

    layer_fwd4<1, 0 >(b, wf, wsB, 0, eb, lane, quad, srcA, srcB, mtbase);  // 32->128
    layer_fwd4<4, 8 >(b, wf, wsB, 1, eb, lane, quad, srcA, srcB, mtbase);  // 128->128
    layer_fwd4<4, 40>(b, wf, wsB, 2, eb, lane, quad, srcA, srcB, mtbase);  // 128->128
    layer_fwd4<4, 72>(b, wf, wsB, 3, eb, lane, quad, srcA, srcB, mtbase);  // 128->128

    // ---- output layer: M=16 (4 real), mt=0 only, no ReLU ----
    f32x4 biaso = *(const f32x4*)&wsB[512 + quad * 4];
    f32x4 acco[4] = {biaso, biaso, biaso, biaso};
    #pragma unroll
    for (int kt = 0; kt < 4; kt++) {
        half8 w = wf[(size_t)(104 + kt) * 64 + lane];
        #pragma unroll
        for (int nt = 0; nt < 4; nt++)
            acco[nt] = __builtin_amdgcn_mfma_f32_16x16x32_f16(w, b[nt][kt], acco[nt], 0, 0, 0);
    }
    if (quad == 0) {
        #pragma unroll
        for (int nt = 0; nt < 4; nt++) {
            f32x4 v;
            #pragma unroll
            for (int r = 0; r < 4; r++) v[r] = acco[nt][r] * INV_SCALE;
            *(f32x4*)(out + (base + nt * 16 + col) * 4) = v;
        }
    }
}

// ---------------------------------------------------------------------------
// Fallback path (ws too small): R1-style fused kernel, unchanged.
// ---------------------------------------------------------------------------
template<int KT, int TOFF, bool RELU>
__device__ __forceinline__ void mlp_layer(_Float16* h, const half8* __restrict__ wf,
                                          const float* __restrict__ wsB, int layerIdx,
                                          int m0, int lane)
{
    const int col = lane & 15, quad = lane >> 4;
    const int sw = (col & 3) << 3;
    half8 a[2][KT];
    #pragma unroll
    for (int mt = 0; mt < 2; mt++)
        #pragma unroll
        for (int kt = 0; kt < KT; kt++)
            a[mt][kt] = *(const half8*)&h[(m0 + mt * 16 + col) * HSTRIDE + ((kt * 32 + quad * 8) ^ sw)];
    f32x4 acc[2][8];
    #pragma unroll
    for (int nt = 0; nt < 8; nt++) {
        float bv = wsB[layerIdx * 128 + nt * 16 + col];
        acc[0][nt] = (f32x4){bv, bv, bv, bv};
        acc[1][nt] = (f32x4){bv, bv, bv, bv};
    }
    #pragma unroll
    for (int nt = 0; nt < 8; nt++) {
        half8 b[KT];
        #pragma unroll
        for (int kt = 0; kt < KT; kt++)
            b[kt] = wf[(size_t)(TOFF + nt * KT + kt) * 64 + lane];
        #pragma unroll
        for (int mt = 0; mt < 2; mt++)
            #pragma unroll
            for (int kt = 0; kt < KT; kt++)
                acc[mt][nt] = __builtin_amdgcn_mfma_f32_16x16x32_f16(a[mt][kt], b[kt], acc[mt][nt], 0, 0, 0);
    }
    #pragma unroll
    for (int mt = 0; mt < 2; mt++)
        #pragma unroll
        for (int nt = 0; nt < 8; nt++) {
            f32x4 v = acc[mt][nt];
            #pragma unroll
            for (int r = 0; r < 4; r++) {
                float x = v[r];
                if (RELU) x = fmaxf(x, 0.0f);
                h[(m0 + mt * 16 + quad * 4 + r) * HSTRIDE + ((nt * 16 + col) ^ (r << 3))] = (_Float16)x;
            }
        }
}

__global__ __launch_bounds__(256, 2) void fused_kernel(
    const float* __restrict__ pos, const float* __restrict__ bmn, const float* __restrict__ bmx,
    const float* __restrict__ tables, const half8* __restrict__ wf, const float* __restrict__ wsB,
    float* __restrict__ out)
{
    __shared__ _Float16 hbuf[128 * HSTRIDE];
    __shared__ float outstage[512];
    const int t = threadIdx.x;
    const long base = (long)blockIdx.x * 128;
    {
        const int p = t >> 1, hh = t & 1;
        const long gp = base + p;
        const float b0x = bmn[0], b0y = bmn[1], b0z = bmn[2];
        const float nx = (pos[gp * 3 + 0] - b0x) / (bmx[0] - b0x);
        const float ny = (pos[gp * 3 + 1] - b0y) / (bmx[1] - b0y);
        const float nz = (pos[gp * 3 + 2] - b0z) / (bmx[2] - b0z);
        constexpr float RLO[8] = {16.f, 20.f, 25.f, 32.f, 40.f, 50.f, 64.f, 80.f};
        constexpr float RHI[8] = {101.f, 128.f, 161.f, 203.f, 256.f, 322.f, 406.f, 512.f};
        half8 fa, fb;
        #pragma unroll
        for (int li = 0; li < 8; li++) {
            const float res = hh ? RHI[li] : RLO[li];
            const float* tbl = tables + ((size_t)(hh * 8 + li) << 20);
            float xs = nx * res, ys = ny * res, zs = nz * res;
            float fx = floorf(xs), fy = floorf(ys), fz = floorf(zs);
            unsigned xi = (unsigned)fx, yi = (unsigned)fy, zi = (unsigned)fz;
            float tx = xs - fx, ty = ys - fy, tz = zs - fz;
            unsigned hx[2] = {xi, xi + 1u};
            unsigned hy[2] = {yi * 2654435761u, (yi + 1u) * 2654435761u};
            unsigned hz[2] = {zi * 805459861u, (zi + 1u) * 805459861u};
            float wx[2] = {1.0f - tx, tx}, wy[2] = {1.0f - ty, ty}, wz[2] = {1.0f - tz, tz};
            float a0 = 0.0f, a1 = 0.0f;
            #pragma unroll
            for (int c = 0; c < 8; c++) {
                unsigned hsh = hx[c & 1] ^ hy[(c >> 1) & 1] ^ hz[c >> 2];
                unsigned idx = hsh & TMASK;
                f32x2 f = *(const f32x2*)(tbl + (size_t)idx * 2);
                float w = wx[c & 1] * wy[(c >> 1) & 1] * wz[c >> 2];
                a0 += w * f.x;
                a1 += w * f.y;
            }
            if (li < 4) { fa[2 * li]       = (_Float16)(a0 * SCALE); fa[2 * li + 1]       = (_Float16)(a1 * SCALE); }
            else        { fb[2 * (li - 4)] = (_Float16)(a0 * SCALE); fb[2 * (li - 4) + 1] = (_Float16)(a1 * SCALE); }
        }
        const int sw = (p & 3) << 3;
        *(half8*)&hbuf[p * HSTRIDE + ((hh * 16) ^ sw)]       = fa;
        *(half8*)&hbuf[p * HSTRIDE + (((hh * 16) + 8) ^ sw)] = fb;
    }
    __syncthreads();
    {
        const int lane = t & 63;
        const int m0 = (t >> 6) * 32;
        mlp_layer<1, 0,   true>(hbuf, wf, wsB, 0, m0, lane);
        mlp_layer<4, 8,   true>(hbuf, wf, wsB, 1, m0, lane);
        mlp_layer<4, 40,  true>(hbuf, wf, wsB, 2, m0, lane);
        mlp_layer<4, 72,  true>(hbuf, wf, wsB, 3, m0, lane);
        const int col = lane & 15, quad = lane >> 4;
        const int sw = (col & 3) << 3;
        half8 a[2][4];
        #pragma unroll
        for (int mt = 0; mt < 2; mt++)
            #pragma unroll
            for (int kt = 0; kt < 4; kt++)
                a[mt][kt] = *(const half8*)&hbuf[(m0 + mt * 16 + col) * HSTRIDE + ((kt * 32 + quad * 8) ^ sw)];
        float bv = wsB[512 + col];
        f32x4 acc[2] = {(f32x4){bv, bv, bv, bv}, (f32x4){bv, bv, bv, bv}};
        #pragma unroll
        for (int kt = 0; kt < 4; kt++) {
            half8 bfr = wf[(size_t)(104 + kt) * 64 + lane];
            #pragma unroll
            for (int mt = 0; mt < 2; mt++)
                acc[mt] = __builtin_amdgcn_mfma_f32_16x16x32_f16(a[mt][kt], bfr, acc[mt], 0, 0, 0);
        }
        if (col < 4) {
            #pragma unroll
            for (int mt = 0; mt < 2; mt++)
                #pragma unroll
                for (int r = 0; r < 4; r++)
                    outstage[(m0 + mt * 16 + quad * 4 + r) * 4 + col] = acc[mt][r] * INV_SCALE;
        }
    }
    __syncthreads();
    if (t < 128) {
        f32x4 v = ((const f32x4*)outstage)[t];
        *(f32x4*)(out + (base + t) * 4) = v;
    }
}

extern "C" void kernel_launch(void* const* d_in, const int* in_sizes, int n_in,
                              void* d_out, int out_size, void* d_ws, size_t ws_size,
                              hipStream_t stream) {
    const float* pos    = (const float*)d_in[0];
    const float* bmn    = (const float*)d_in[1];
    const float* bmx    = (const float*)d_in[2];
    const float* tables = (const float*)d_in[3];
    const float* W0 = (const float*)d_in[4];
    const float* b0 = (const float*)d_in[5];
    const float* W1 = (const float*)d_in[6];
    const float* b1 = (const float*)d_in[7];
    const float* W2 = (const float*)d_in[8];
    const float* b2 = (const float*)d_in[9];
    const float* W3 = (const float*)d_in[10];
    const float* b3 = (const float*)d_in[11];
    const float* Wm = (const float*)d_in[12];
    const float* bm = (const float*)d_in[13];

    const int N = in_sizes[0] / 3;
    const size_t featBytes    = (size_t)N * 16 * 4;             // [16][N] f16x2
    const size_t tabFineBytes = (size_t)8 * 524288 * 2 * 2;     // 16 MB f16, levels 8-15
    const size_t denseBytes   = ((size_t)DTOTAL * 4 + 255) & ~(size_t)255;  // ~4.5 MB
    const size_t need = featBytes + tabFineBytes + denseBytes + 110592 + 2112;

    if (ws_size >= need && (N % 256) == 0) {
        _Float16* feat  = (_Float16*)d_ws;
        _Float16* tabF  = (_Float16*)((char*)d_ws + featBytes);
        unsigned* dense = (unsigned*)((char*)d_ws + featBytes + tabFineBytes);
        _Float16* wsW   = (_Float16*)((char*)d_ws + featBytes + tabFineBytes + denseBytes);
        float*    wsB   = (float*)((char*)d_ws + featBytes + tabFineBytes + denseBytes + 110592);
        prep_kernel<<<8192 + 30, 256, 0, stream>>>(W0, W1, W2, W3, Wm, b0, b1, b2, b3, bm,
                                                   wsW, wsB, tables + (size_t)8 * 524288 * 2,
                                                   tabF, 8192);
        dense_build<<<(DTOTAL + 255) / 256, 256, 0, stream>>>(tables, dense);
        encode_kernel<<<(N / 256) * 8, 256, 0, stream>>>(pos, bmn, bmx, tabF, dense, feat, N);
        mlp_kernel<<<N / 256, 256, 0, stream>>>((const unsigned*)feat, (const half8*)wsW,
                                                wsB, (float*)d_out, N);
    } else {
        _Float16* wsW = (_Float16*)d_ws;
        float*    wsB = (float*)((char*)d_ws + 110592);
        prep_kernel<<<30, 256, 0, stream>>>(W0, W1, W2, W3, Wm, b0, b1, b2, b3, bm,
                                            wsW, wsB, tables, (_Float16*)nullptr, 0);
        fused_kernel<<<N / 128, 256, 0, stream>>>(pos, bmn, bmx, tables,
                                                  (const half8*)wsW, wsB, (float*)d_out);
    }
}

// Round 8
// 615.584 us; speedup vs baseline: 1.6112x; 1.0106x over previous
//
#include <hip/hip_runtime.h>

typedef _Float16 half8 __attribute__((ext_vector_type(8)));
typedef _Float16 half4 __attribute__((ext_vector_type(4)));
typedef _Float16 half2 __attribute__((ext_vector_type(2)));
typedef float    f32x4 __attribute__((ext_vector_type(4)));
typedef float    f32x2 __attribute__((ext_vector_type(2)));
typedef unsigned u32x2 __attribute__((ext_vector_type(2)));
typedef unsigned u32x4 __attribute__((ext_vector_type(4)));

#define TMASK ((1u << 19) - 1u)       // T = 2^19
#define HSTRIDE 136                    // fallback-kernel LDS stride
constexpr float SCALE = 65536.0f;      // activation scale: keeps f16 out of subnormal range
constexpr float INV_SCALE = 1.0f / 65536.0f;

// Dense-remap geometry, coarse levels 0..7 (s = res+2 guards x=1.0 edge).
// R8: 16B slots of 4 x-consecutive f16x2 entries; sx4 = ceil(s/4) slots/row.
__device__ __constant__ unsigned SC_TAB[8]   = {18, 22, 27, 34, 42, 52, 66, 82};
__device__ __constant__ unsigned SX4_TAB[8]  = {5, 6, 7, 9, 11, 13, 17, 21};
__device__ __constant__ unsigned DOFF16_TAB[8] = {0, 1620, 4524, 9627, 20031, 39435, 74587, 148639};
#define DSLOT_TOTAL 289843u

// ---------------------------------------------------------------------------
// Prep: (a) fp32 FINE tables (levels 8-15) -> f16 pre-scaled, (b) weights ->
// fragment-native f16 layout + biases. (unchanged)
// ---------------------------------------------------------------------------
__global__ void prep_kernel(const float* __restrict__ W0, const float* __restrict__ W1,
                            const float* __restrict__ W2, const float* __restrict__ W3,
                            const float* __restrict__ Wm,
                            const float* __restrict__ b0, const float* __restrict__ b1,
                            const float* __restrict__ b2, const float* __restrict__ b3,
                            const float* __restrict__ bm,
                            _Float16* __restrict__ wsW, float* __restrict__ wsB,
                            const float* __restrict__ tabSrc, _Float16* __restrict__ tabF,
                            int tabBlocks)
{
    if ((int)blockIdx.x < tabBlocks) {
        size_t i = (size_t)blockIdx.x * 256 + threadIdx.x;
        f32x4 v = ((const f32x4*)tabSrc)[i];
        half4 o;
        o[0] = (_Float16)(v.x * SCALE);
        o[1] = (_Float16)(v.y * SCALE);
        o[2] = (_Float16)(v.z * SCALE);
        o[3] = (_Float16)(v.w * SCALE);
        ((half4*)tabF)[i] = o;
        return;
    }
    int gid = ((int)blockIdx.x - tabBlocks) * 256 + threadIdx.x;
    if (gid < 6912) {                       // 108 tiles * 64 lanes
        int tile = gid >> 6, lane = gid & 63;
        const float* W; int K, N, toff;
        if (tile < 8)        { W = W0; K = 32;  N = 128; toff = 0;   }
        else if (tile < 40)  { W = W1; K = 128; N = 128; toff = 8;   }
        else if (tile < 72)  { W = W2; K = 128; N = 128; toff = 40;  }
        else if (tile < 104) { W = W3; K = 128; N = 128; toff = 72;  }
        else                 { W = Wm; K = 128; N = 4;   toff = 104; }
        int tt = tile - toff;
        int KT = K >> 5;
        int nt = tt / KT, kt = tt - nt * KT;
        int n = nt * 16 + (lane & 15);
        int kbase = kt * 32 + (lane >> 4) * 8;
        half8 v;
        #pragma unroll
        for (int j = 0; j < 8; j++) {
            int k = kbase + j;
            float w = (n < N) ? W[k * N + n] : 0.0f;
            v[j] = (_Float16)w;
        }
        *(half8*)(wsW + (size_t)gid * 8) = v;
    } else if (gid < 6912 + 528) {
        int i = gid - 6912;
        float v;
        if (i < 512) {
            int layer = i >> 7, n = i & 127;
            const float* b = (layer == 0) ? b0 : (layer == 1) ? b1 : (layer == 2) ? b2 : b3;
            v = b[n] * SCALE;
        } else {
            int n = i - 512;
            v = (n < 4) ? bm[n] * SCALE : 0.0f;
        }
        wsB[i] = v;
    }
}

// ---------------------------------------------------------------------------
// Dense remap build, 16B-slot layout: slot (x>>2, y, z) holds entries for
// x = 4*(x>>2)+{0..3}; value = f16(table[l][hash(x,y,z) % T]) (bit-identical
// to hashed lookup). Pad entries (x >= s) are never selected.
// One thread per dword (4 per slot).
// ---------------------------------------------------------------------------
__global__ void dense_build(const float* __restrict__ tables, unsigned* __restrict__ dense)
{
    unsigned e = blockIdx.x * 256 + threadIdx.x;
    if (e >= DSLOT_TOTAL * 4u) return;
    unsigned slot = e >> 2, j = e & 3u;
    int l = 0;
    #pragma unroll
    for (int i = 1; i < 8; i++) l += (slot >= DOFF16_TAB[i]) ? 1 : 0;
    unsigned local = slot - DOFF16_TAB[l];
    unsigned s = SC_TAB[l], sx4 = SX4_TAB[l];
    unsigned plane = sx4 * s;
    unsigned z = local / plane;
    unsigned rem = local - z * plane;
    unsigned y = rem / sx4;
    unsigned xs = rem - y * sx4;
    unsigned x = xs * 4u + j;
    unsigned h = (x ^ (y * 2654435761u) ^ (z * 805459861u)) & TMASK;
    const float* src = tables + ((size_t)l * 524288u + h) * 2;
    half2 o; o[0] = (_Float16)(src[0] * SCALE); o[1] = (_Float16)(src[1] * SCALE);
    union { half2 h2; unsigned u; } cv; cv.h2 = o;
    dense[e] = cv.u;
}

// ---------------------------------------------------------------------------
// Encode kernel R8: 2 points/thread (2x memory-level parallelism; encode is
// latency x concurrency bound per R5/R6 evidence) + 16B-slot coarse loads
// (4 + 0.25*4 avg scattered loads vs 8). lvl0 = bid&7 keeps XCD affinity.
// Issue order p0-fine, p0-coarse, p1-fine, p1-coarse; consume p0 then p1 so
// p1's loads stay in flight during p0's consumption.
// ---------------------------------------------------------------------------
__global__ __launch_bounds__(256, 4) void encode_kernel(
    const float* __restrict__ pos, const float* __restrict__ bmn, const float* __restrict__ bmx,
    const _Float16* __restrict__ tabFine, const u32x4* __restrict__ dense16,
    _Float16* __restrict__ feat, int npts)
{
    const int lvl0 = (int)(blockIdx.x & 7);
    const int t = (int)threadIdx.x;
    const long p0 = (long)(blockIdx.x >> 3) * 512 + t;    // second point: p0 + 256
    const float bx = bmn[0], by = bmn[1], bz = bmn[2];
    const float dxr = bmx[0] - bx, dyr = bmx[1] - by, dzr = bmx[2] - bz;
    constexpr float RESL[16] = {16.f, 20.f, 25.f, 32.f, 40.f, 50.f, 64.f, 80.f,
                                101.f, 128.f, 161.f, 203.f, 256.f, 322.f, 406.f, 512.f};
    const int l1 = lvl0 + 8;
    const _Float16* tblB = tabFine + ((size_t)lvl0 << 20);
    const float resF = RESL[l1], resC = RESL[lvl0];
    const unsigned s   = SC_TAB[lvl0];
    const unsigned sx4 = SX4_TAB[lvl0];
    const unsigned plane = sx4 * s;
    const u32x4* dptr = dense16 + DOFF16_TAB[lvl0];

    // ---- per-point state ----
    unsigned fSlot[2][4], fOdd[2][4], cBase[2][4];
    unsigned peM[2], kC[2];
    bool oddF[2], nx3[2];
    float fF[2][3], fC[2][3];   // fracs fine/coarse

    #pragma unroll
    for (int pt = 0; pt < 2; pt++) {
        const long p = p0 + pt * 256;
        const float nx = (pos[p * 3 + 0] - bx) / dxr;
        const float ny = (pos[p * 3 + 1] - by) / dyr;
        const float nz = (pos[p * 3 + 2] - bz) / dzr;
        {   // fine (hashed)
            float xs = nx * resF, ys = ny * resF, zs = nz * resF;
            float fx = floorf(xs), fy = floorf(ys), fz = floorf(zs);
            unsigned xi = (unsigned)fx, yi = (unsigned)fy, zi = (unsigned)fz;
            fF[pt][0] = xs - fx; fF[pt][1] = ys - fy; fF[pt][2] = zs - fz;
            unsigned hy0 = yi * 2654435761u, hy1 = (yi + 1u) * 2654435761u;
            unsigned hz0 = zi * 805459861u,  hz1 = (zi + 1u) * 805459861u;
            unsigned hyz[4] = {hy0 ^ hz0, hy1 ^ hz0, hy0 ^ hz1, hy1 ^ hz1};
            unsigned e = (xi + 1u) & ~1u, o = xi | 1u;
            oddF[pt] = (xi & 1u) != 0u;
            unsigned m = 0;
            #pragma unroll
            for (int g = 0; g < 4; g++) {
                unsigned ie = (e ^ hyz[g]) & TMASK;
                fSlot[pt][g] = ie & ~1u;
                m |= (ie & 1u) << g;
                fOdd[pt][g] = (o ^ hyz[g]) & TMASK;
            }
            peM[pt] = m;
        }
        {   // coarse (dense 16B slots)
            float xs = nx * resC, ys = ny * resC, zs = nz * resC;
            float fx = floorf(xs), fy = floorf(ys), fz = floorf(zs);
            unsigned xi = (unsigned)fx, yi = (unsigned)fy, zi = (unsigned)fz;
            fC[pt][0] = xs - fx; fC[pt][1] = ys - fy; fC[pt][2] = zs - fz;
            unsigned b00 = (xi >> 2) + sx4 * yi + plane * zi;
            cBase[pt][0] = b00;
            cBase[pt][1] = b00 + sx4;
            cBase[pt][2] = b00 + plane;
            cBase[pt][3] = b00 + plane + sx4;
            kC[pt] = xi & 3u;
            nx3[pt] = (kC[pt] == 3u);
        }
    }

    // ---- issue loads: p0 batch then p1 batch ----
    u32x2 fS[2][4]; u32x4 cS[2][4]; unsigned fO[2][4], cN[2][4];
    #pragma unroll
    for (int pt = 0; pt < 2; pt++) {
        #pragma unroll
        for (int g = 0; g < 4; g++)
            fS[pt][g] = *(const u32x2*)(tblB + (size_t)fSlot[pt][g] * 2);
        #pragma unroll
        for (int g = 0; g < 4; g++)
            cS[pt][g] = dptr[cBase[pt][g]];
        if (oddF[pt]) {
            #pragma unroll
            for (int g = 0; g < 4; g++)
                fO[pt][g] = *(const unsigned*)(tblB + (size_t)fOdd[pt][g] * 2);
        }
        if (nx3[pt]) {
            #pragma unroll
            for (int g = 0; g < 4; g++)
                cN[pt][g] = *(const unsigned*)(dptr + cBase[pt][g] + 1);
        }
    }

    // ---- consume p0 then p1 (p1 loads remain outstanding during p0) ----
    #pragma unroll
    for (int pt = 0; pt < 2; pt++) {
        const long p = p0 + pt * 256;
        {   // fine
            float tx = fF[pt][0], ty = fF[pt][1], tz = fF[pt][2];
            float wyz[4] = {(1.0f - ty) * (1.0f - tz), ty * (1.0f - tz),
                            (1.0f - ty) * tz,          ty * tz};
            float b0 = 0.0f, b1 = 0.0f;
            #pragma unroll
            for (int g = 0; g < 4; g++) {
                union { unsigned u; half2 h; } lo, hi, ov;
                lo.u = fS[pt][g][0]; hi.u = fS[pt][g][1];
                bool pe = ((peM[pt] >> g) & 1u) != 0u;
                half2 fe  = pe ? hi.h : lo.h;
                half2 fe1 = pe ? lo.h : hi.h;
                ov.u = oddF[pt] ? fO[pt][g] : 0u;
                half2 fx0 = oddF[pt] ? ov.h : fe;
                half2 fx1 = oddF[pt] ? fe : fe1;
                float w0 = wyz[g] * (1.0f - tx), w1 = wyz[g] * tx;
                b0 += w0 * (float)fx0[0] + w1 * (float)fx1[0];
                b1 += w0 * (float)fx0[1] + w1 * (float)fx1[1];
            }
            half2 ov2; ov2[0] = (_Float16)b0; ov2[1] = (_Float16)b1;
            union { half2 h; unsigned u; } cv; cv.h = ov2;
            __builtin_nontemporal_store(cv.u, (unsigned*)(feat + ((size_t)l1 * npts + p) * 2));
        }
        {   // coarse
            float tx = fC[pt][0], ty = fC[pt][1], tz = fC[pt][2];
            float wyz[4] = {(1.0f - ty) * (1.0f - tz), ty * (1.0f - tz),
                            (1.0f - ty) * tz,          ty * tz};
            unsigned k = kC[pt];
            unsigned kp1 = (k < 3u) ? (k + 1u) : 0u;
            float a0 = 0.0f, a1 = 0.0f;
            #pragma unroll
            for (int g = 0; g < 4; g++) {
                union { unsigned u; half2 h; } u0, u1;
                u0.u = cS[pt][g][k];
                u1.u = nx3[pt] ? cN[pt][g] : cS[pt][g][kp1];
                float w0 = wyz[g] * (1.0f - tx), w1 = wyz[g] * tx;
                a0 += w0 * (float)u0.h[0] + w1 * (float)u1.h[0];
                a1 += w0 * (float)u0.h[1] + w1 * (float)u1.h[1];
            }
            half2 ov2; ov2[0] = (_Float16)a0; ov2[1] = (_Float16)a1;
            union { half2 h; unsigned u; } cv; cv.h = ov2;
            __builtin_nontemporal_store(cv.u, (unsigned*)(feat + ((size_t)lvl0 * npts + p) * 2));
        }
    }
}

// ---------------------------------------------------------------------------
// MLP kernel (R7, unchanged): role-swapped MFMA, 64 points/wave, per-mt
// publish, b128 exchange, wave-private, NO barriers.
// ---------------------------------------------------------------------------
#define ELANE 68   // dwords per lane: 64 payload + 4 pad; 272B (16B-aligned)

template<int KT, int TOFF>
__device__ __forceinline__ void layer_fwd4(half8 b[4][4], const half8* __restrict__ wf,
                                           const float* __restrict__ wsB, int li,
                                           unsigned* __restrict__ eb, int lane, int quad,
                                           unsigned srcA, unsigned srcB, int mtbase)
{
    unsigned* wptr = eb + lane * ELANE;
    #pragma unroll
    for (int mt = 0; mt < 8; mt++) {
        f32x4 bias = *(const f32x4*)&wsB[li * 128 + mt * 16 + quad * 4];
        half8 w[KT];
        #pragma unroll
        for (int kt = 0; kt < KT; kt++)
            w[kt] = wf[(size_t)(TOFF + mt * KT + kt) * 64 + lane];
        f32x4 acc[4] = {bias, bias, bias, bias};
        #pragma unroll
        for (int nt = 0; nt < 4; nt++)
            #pragma unroll
            for (int kt = 0; kt < KT; kt++)
                acc[nt] = __builtin_amdgcn_mfma_f32_16x16x32_f16(w[kt], b[nt][kt], acc[nt], 0, 0, 0);
        #pragma unroll
        for (int np = 0; np < 2; np++) {
            union { _Float16 h[8]; u32x4 v; } pk;
            #pragma unroll
            for (int r = 0; r < 4; r++) {
                pk.h[r]     = (_Float16)fmaxf(acc[2 * np][r],     0.0f);
                pk.h[4 + r] = (_Float16)fmaxf(acc[2 * np + 1][r], 0.0f);
            }
            *(u32x4*)(wptr + mt * 8 + np * 4) = pk.v;
        }
    }
    #pragma unroll
    for (int ktp = 0; ktp < 4; ktp++) {
        int mt = 2 * ktp + mtbase;
        u32x4 rA0 = *(const u32x4*)(eb + srcA * ELANE + mt * 8);
        u32x4 rA1 = *(const u32x4*)(eb + srcA * ELANE + mt * 8 + 4);
        u32x4 rB0 = *(const u32x4*)(eb + srcB * ELANE + mt * 8);
        u32x4 rB1 = *(const u32x4*)(eb + srcB * ELANE + mt * 8 + 4);
        union { u32x4 v; half8 h; } c0, c1, c2, c3;
        c0.v = (u32x4){rA0[0], rA0[1], rB0[0], rB0[1]};
        c1.v = (u32x4){rA0[2], rA0[3], rB0[2], rB0[3]};
        c2.v = (u32x4){rA1[0], rA1[1], rB1[0], rB1[1]};
        c3.v = (u32x4){rA1[2], rA1[3], rB1[2], rB1[3]};
        b[0][ktp] = c0.h;
        b[1][ktp] = c1.h;
        b[2][ktp] = c2.h;
        b[3][ktp] = c3.h;
    }
}

__global__ __launch_bounds__(256) void mlp_kernel(
    const unsigned* __restrict__ feat32, const half8* __restrict__ wf,
    const float* __restrict__ wsB, float* __restrict__ out, int npts)
{
    __shared__ __align__(16) unsigned ebuf[4 * 64 * ELANE];
    const int t = threadIdx.x;
    const int lane = t & 63, wv = t >> 6;
    const int col = lane & 15, quad = lane >> 4;
    const long base = (long)blockIdx.x * 256 + wv * 64;
    unsigned* eb = ebuf + wv * (64 * ELANE);
    const int q1 = 2 * (quad & 1);
    const unsigned srcA = (unsigned)(col + 16 * q1);
    const unsigned srcB = (unsigned)(col + 16 * (q1 + 1));
    const int mtbase = quad >> 1;

    half8 b[4][4];
    #pragma unroll
    for (int nt = 0; nt < 4; nt++) {
        const long pt = base + nt * 16 + col;
        union { unsigned u4[4]; half8 v; } cv;
        #pragma unroll
        for (int jj = 0; jj < 4; jj++)
            cv.u4[jj] = feat32[(size_t)(quad * 4 + jj) * npts + pt];
        b[nt][0] = cv.v;
    }

    layer_fwd4<1, 0 >(b, wf, wsB, 0, eb, lane, quad, srcA, srcB, mtbase);  // 32->128
    layer_fwd4<4, 8 >(b, wf, wsB, 1, eb, lane, quad, srcA, srcB, mtbase);  // 128->128
    layer_fwd4<4, 40>(b, wf, wsB, 2, eb, lane, quad, srcA, srcB, mtbase);  // 128->128
    layer_fwd4<4, 72>(b, wf, wsB, 3, eb, lane, quad, srcA, srcB, mtbase);  // 128->128

    f32x4 biaso = *(const f32x4*)&wsB[512 + quad * 4];
    f32x4 acco[4] = {biaso, biaso, biaso, biaso};
    #pragma unroll
    for (int kt = 0; kt < 4; kt++) {
        half8 w = wf[(size_t)(104 + kt) * 64 + lane];
        #pragma unroll
        for (int nt = 0; nt < 4; nt++)
            acco[nt] = __builtin_amdgcn_mfma_f32_16x16x32_f16(w, b[nt][kt], acco[nt], 0, 0, 0);
    }
    if (quad == 0) {
        #pragma unroll
        for (int nt = 0; nt < 4; nt++) {
            f32x4 v;
            #pragma unroll
            for (int r = 0; r < 4; r++) v[r] = acco[nt][r] * INV_SCALE;
            *(f32x4*)(out + (base + nt * 16 + col) * 4) = v;
        }
    }
}

// ---------------------------------------------------------------------------
// Fallback path (ws too small): R1-style fused kernel, unchanged.
// ---------------------------------------------------------------------------
template<int KT, int TOFF, bool RELU>
__device__ __forceinline__ void mlp_layer(_Float16* h, const half8* __restrict__ wf,
                                          const float* __restrict__ wsB, int layerIdx,
                                          int m0, int lane)
{
    const int col = lane & 15, quad = lane >> 4;
    const int sw = (col & 3) << 3;
    half8 a[2][KT];
    #pragma unroll
    for (int mt = 0; mt < 2; mt++)
        #pragma unroll
        for (int kt = 0; kt < KT; kt++)
            a[mt][kt] = *(const half8*)&h[(m0 + mt * 16 + col) * HSTRIDE + ((kt * 32 + quad * 8) ^ sw)];
    f32x4 acc[2][8];
    #pragma unroll
    for (int nt = 0; nt < 8; nt++) {
        float bv = wsB[layerIdx * 128 + nt * 16 + col];
        acc[0][nt] = (f32x4){bv, bv, bv, bv};
        acc[1][nt] = (f32x4){bv, bv, bv, bv};
    }
    #pragma unroll
    for (int nt = 0; nt < 8; nt++) {
        half8 b[KT];
        #pragma unroll
        for (int kt = 0; kt < KT; kt++)
            b[kt] = wf[(size_t)(TOFF + nt * KT + kt) * 64 + lane];
        #pragma unroll
        for (int mt = 0; mt < 2; mt++)
            #pragma unroll
            for (int kt = 0; kt < KT; kt++)
                acc[mt][nt] = __builtin_amdgcn_mfma_f32_16x16x32_f16(a[mt][kt], b[kt], acc[mt][nt], 0, 0, 0);
    }
    #pragma unroll
    for (int mt = 0; mt < 2; mt++)
        #pragma unroll
        for (int nt = 0; nt < 8; nt++) {
            f32x4 v = acc[mt][nt];
            #pragma unroll
            for (int r = 0; r < 4; r++) {
                float x = v[r];
                if (RELU) x = fmaxf(x, 0.0f);
                h[(m0 + mt * 16 + quad * 4 + r) * HSTRIDE + ((nt * 16 + col) ^ (r << 3))] = (_Float16)x;
            }
        }
}

__global__ __launch_bounds__(256, 2) void fused_kernel(
    const float* __restrict__ pos, const float* __restrict__ bmn, const float* __restrict__ bmx,
    const float* __restrict__ tables, const half8* __restrict__ wf, const float* __restrict__ wsB,
    float* __restrict__ out)
{
    __shared__ _Float16 hbuf[128 * HSTRIDE];
    __shared__ float outstage[512];
    const int t = threadIdx.x;
    const long base = (long)blockIdx.x * 128;
    {
        const int p = t >> 1, hh = t & 1;
        const long gp = base + p;
        const float b0x = bmn[0], b0y = bmn[1], b0z = bmn[2];
        const float nx = (pos[gp * 3 + 0] - b0x) / (bmx[0] - b0x);
        const float ny = (pos[gp * 3 + 1] - b0y) / (bmx[1] - b0y);
        const float nz = (pos[gp * 3 + 2] - b0z) / (bmx[2] - b0z);
        constexpr float RLO[8] = {16.f, 20.f, 25.f, 32.f, 40.f, 50.f, 64.f, 80.f};
        constexpr float RHI[8] = {101.f, 128.f, 161.f, 203.f, 256.f, 322.f, 406.f, 512.f};
        half8 fa, fb;
        #pragma unroll
        for (int li = 0; li < 8; li++) {
            const float res = hh ? RHI[li] : RLO[li];
            const float* tbl = tables + ((size_t)(hh * 8 + li) << 20);
            float xs = nx * res, ys = ny * res, zs = nz * res;
            float fx = floorf(xs), fy = floorf(ys), fz = floorf(zs);
            unsigned xi = (unsigned)fx, yi = (unsigned)fy, zi = (unsigned)fz;
            float tx = xs - fx, ty = ys - fy, tz = zs - fz;
            unsigned hx[2] = {xi, xi + 1u};
            unsigned hy[2] = {yi * 2654435761u, (yi + 1u) * 2654435761u};
            unsigned hz[2] = {zi * 805459861u, (zi + 1u) * 805459861u};
            float wx[2] = {1.0f - tx, tx}, wy[2] = {1.0f - ty, ty}, wz[2] = {1.0f - tz, tz};
            float a0 = 0.0f, a1 = 0.0f;
            #pragma unroll
            for (int c = 0; c < 8; c++) {
                unsigned hsh = hx[c & 1] ^ hy[(c >> 1) & 1] ^ hz[c >> 2];
                unsigned idx = hsh & TMASK;
                f32x2 f = *(const f32x2*)(tbl + (size_t)idx * 2);
                float w = wx[c & 1] * wy[(c >> 1) & 1] * wz[c >> 2];
                a0 += w * f.x;
                a1 += w * f.y;
            }
            if (li < 4) { fa[2 * li]       = (_Float16)(a0 * SCALE); fa[2 * li + 1]       = (_Float16)(a1 * SCALE); }
            else        { fb[2 * (li - 4)] = (_Float16)(a0 * SCALE); fb[2 * (li - 4) + 1] = (_Float16)(a1 * SCALE); }
        }
        const int sw = (p & 3) << 3;
        *(half8*)&hbuf[p * HSTRIDE + ((hh * 16) ^ sw)]       = fa;
        *(half8*)&hbuf[p * HSTRIDE + (((hh * 16) + 8) ^ sw)] = fb;
    }
    __syncthreads();
    {
        const int lane = t & 63;
        const int m0 = (t >> 6) * 32;
        mlp_layer<1, 0,   true>(hbuf, wf, wsB, 0, m0, lane);
        mlp_layer<4, 8,   true>(hbuf, wf, wsB, 1, m0, lane);
        mlp_layer<4, 40,  true>(hbuf, wf, wsB, 2, m0, lane);
        mlp_layer<4, 72,  true>(hbuf, wf, wsB, 3, m0, lane);
        const int col = lane & 15, quad = lane >> 4;
        const int sw = (col & 3) << 3;
        half8 a[2][4];
        #pragma unroll
        for (int mt = 0; mt < 2; mt++)
            #pragma unroll
            for (int kt = 0; kt < 4; kt++)
                a[mt][kt] = *(const half8*)&hbuf[(m0 + mt * 16 + col) * HSTRIDE + ((kt * 32 + quad * 8) ^ sw)];
        float bv = wsB[512 + col];
        f32x4 acc[2] = {(f32x4){bv, bv, bv, bv}, (f32x4){bv, bv, bv, bv}};
        #pragma unroll
        for (int kt = 0; kt < 4; kt++) {
            half8 bfr = wf[(size_t)(104 + kt) * 64 + lane];
            #pragma unroll
            for (int mt = 0; mt < 2; mt++)
                acc[mt] = __builtin_amdgcn_mfma_f32_16x16x32_f16(a[mt][kt], bfr, acc[mt], 0, 0, 0);
        }
        if (col < 4) {
            #pragma unroll
            for (int mt = 0; mt < 2; mt++)
                #pragma unroll
                for (int r = 0; r < 4; r++)
                    outstage[(m0 + mt * 16 + quad * 4 + r) * 4 + col] = acc[mt][r] * INV_SCALE;
        }
    }
    __syncthreads();
    if (t < 128) {
        f32x4 v = ((const f32x4*)outstage)[t];
        *(f32x4*)(out + (base + t) * 4) = v;
    }
}

extern "C" void kernel_launch(void* const* d_in, const int* in_sizes, int n_in,
                              void* d_out, int out_size, void* d_ws, size_t ws_size,
                              hipStream_t stream) {
    const float* pos    = (const float*)d_in[0];
    const float* bmn    = (const float*)d_in[1];
    const float* bmx    = (const float*)d_in[2];
    const float* tables = (const float*)d_in[3];
    const float* W0 = (const float*)d_in[4];
    const float* b0 = (const float*)d_in[5];
    const float* W1 = (const float*)d_in[6];
    const float* b1 = (const float*)d_in[7];
    const float* W2 = (const float*)d_in[8];
    const float* b2 = (const float*)d_in[9];
    const float* W3 = (const float*)d_in[10];
    const float* b3 = (const float*)d_in[11];
    const float* Wm = (const float*)d_in[12];
    const float* bm = (const float*)d_in[13];

    const int N = in_sizes[0] / 3;
    const size_t featBytes    = (size_t)N * 16 * 4;             // [16][N] f16x2
    const size_t tabFineBytes = (size_t)8 * 524288 * 2 * 2;     // 16 MB f16, levels 8-15
    const size_t denseBytes   = ((size_t)DSLOT_TOTAL * 16 + 255) & ~(size_t)255;  // ~4.6 MB
    const size_t need = featBytes + tabFineBytes + denseBytes + 110592 + 2112;

    if (ws_size >= need && (N % 512) == 0) {
        _Float16* feat  = (_Float16*)d_ws;
        _Float16* tabF  = (_Float16*)((char*)d_ws + featBytes);
        unsigned* dense = (unsigned*)((char*)d_ws + featBytes + tabFineBytes);
        _Float16* wsW   = (_Float16*)((char*)d_ws + featBytes + tabFineBytes + denseBytes);
        float*    wsB   = (float*)((char*)d_ws + featBytes + tabFineBytes + denseBytes + 110592);
        prep_kernel<<<8192 + 30, 256, 0, stream>>>(W0, W1, W2, W3, Wm, b0, b1, b2, b3, bm,
                                                   wsW, wsB, tables + (size_t)8 * 524288 * 2,
                                                   tabF, 8192);
        dense_build<<<(DSLOT_TOTAL * 4 + 255) / 256, 256, 0, stream>>>(tables, dense);
        encode_kernel<<<(N / 512) * 8, 256, 0, stream>>>(pos, bmn, bmx, tabF,
                                                         (const u32x4*)dense, feat, N);
        mlp_kernel<<<N / 256, 256, 0, stream>>>((const unsigned*)feat, (const half8*)wsW,
                                                wsB, (float*)d_out, N);
    } else {
        _Float16* wsW = (_Float16*)d_ws;
        float*    wsB = (float*)((char*)d_ws + 110592);
        prep_kernel<<<30, 256, 0, stream>>>(W0, W1, W2, W3, Wm, b0, b1, b2, b3, bm,
                                            wsW, wsB, tables, (_Float16*)nullptr, 0);
        fused_kernel<<<N / 128, 256, 0, stream>>>(pos, bmn, bmx, tables,
                                                  (const half8*)wsW, wsB, (float*)d_out);
    }
}